// Round 7
// baseline (336.068 us; speedup 1.0000x reference)
//
#include <hip/hip_runtime.h>
#include <hip/hip_fp16.h>

#define LEAKY 0.2f
#define BSH 7
#define BN 128      // nodes per bucket = 1<<BSH
#define CHUNK 8192  // edges per partition workgroup
#define NBMAX 1024  // max buckets supported by LDS arrays

__device__ __forceinline__ float wave_reduce_add64(float v) {
  #pragma unroll
  for (int m = 1; m < 64; m <<= 1) v += __shfl_xor(v, m, 64);
  return v;
}

__device__ __forceinline__ float leaky(float l) {
  return l >= 0.f ? l : LEAKY * l;
}

// ---------------- Tiled GEMM + fused attention dots (+ fp16 mirror of h) ----------------
template<int K, int CO, int H>
__global__ __launch_bounds__(256)
void gat_gemm2(const float* __restrict__ x, const float* __restrict__ W,
               const float* __restrict__ atts, const float* __restrict__ attd,
               float* __restrict__ h, __half* __restrict__ hh,
               float* __restrict__ sa, float* __restrict__ da, int N) {
  constexpr int CG = CO / 4;
  constexpr int BM = (256 / CG) * 4;
  constexpr int BK = 64;
  constexpr int NK = K / BK;
  constexpr int C = CO / H;

  __shared__ float xs[BM][BK + 4];
  __shared__ float ws[CO][K + 4];

  const int t = (int)threadIdx.x;
  const int cg = t % CG;
  const int ng = t / CG;
  const int n0 = (int)blockIdx.x * BM;

  constexpr int WF4 = CO * K / 4;
  for (int f = t; f < WF4; f += 256) {
    const int r = f / (K / 4), c4 = f % (K / 4);
    *(float4*)&ws[r][c4 * 4] = *(const float4*)(W + (size_t)r * K + c4 * 4);
  }

  float acc[4][4] = {};

  for (int kb = 0; kb < NK; ++kb) {
    __syncthreads();
    constexpr int XF4 = BM * BK / 4;
    for (int f = t; f < XF4; f += 256) {
      const int r = f / (BK / 4), c4 = f % (BK / 4);
      int row = n0 + r; row = row < N ? row : N - 1;
      *(float4*)&xs[r][c4 * 4] = *(const float4*)(x + (size_t)row * K + kb * BK + c4 * 4);
    }
    __syncthreads();
    #pragma unroll
    for (int k = 0; k < BK; k += 4) {
      float4 xa[4], wb[4];
      #pragma unroll
      for (int i = 0; i < 4; ++i) xa[i] = *(const float4*)&xs[ng * 4 + i][k];
      #pragma unroll
      for (int j = 0; j < 4; ++j) wb[j] = *(const float4*)&ws[cg + CG * j][kb * BK + k];
      #pragma unroll
      for (int i = 0; i < 4; ++i) {
        #pragma unroll
        for (int j = 0; j < 4; ++j) {
          acc[i][j] = fmaf(xa[i].x, wb[j].x, acc[i][j]);
          acc[i][j] = fmaf(xa[i].y, wb[j].y, acc[i][j]);
          acc[i][j] = fmaf(xa[i].z, wb[j].z, acc[i][j]);
          acc[i][j] = fmaf(xa[i].w, wb[j].w, acc[i][j]);
        }
      }
    }
  }

  float as_[4], ad_[4];
  #pragma unroll
  for (int j = 0; j < 4; ++j) {
    as_[j] = atts[cg + CG * j];
    ad_[j] = attd[cg + CG * j];
  }
  float ps[4][H] = {}, pd[4][H] = {};
  #pragma unroll
  for (int i = 0; i < 4; ++i) {
    #pragma unroll
    for (int j = 0; j < 4; ++j) {
      const int hd = (CG * j) / C;
      ps[i][hd] = fmaf(acc[i][j], as_[j], ps[i][hd]);
      pd[i][hd] = fmaf(acc[i][j], ad_[j], pd[i][hd]);
    }
  }
  #pragma unroll
  for (int m = 1; m < CG; m <<= 1) {
    #pragma unroll
    for (int i = 0; i < 4; ++i) {
      #pragma unroll
      for (int hd = 0; hd < H; ++hd) {
        ps[i][hd] += __shfl_xor(ps[i][hd], m, 64);
        pd[i][hd] += __shfl_xor(pd[i][hd], m, 64);
      }
    }
  }

  #pragma unroll
  for (int i = 0; i < 4; ++i) {
    const int n = n0 + ng * 4 + i;
    if (n < N) {
      #pragma unroll
      for (int j = 0; j < 4; ++j) {
        h[(size_t)n * CO + cg + CG * j] = acc[i][j];
        hh[(size_t)n * CO + cg + CG * j] = __float2half(acc[i][j]);
      }
      if (cg == 0) {
        #pragma unroll
        for (int hd = 0; hd < H; ++hd) {
          sa[n * H + hd] = ps[i][hd];
          da[n * H + hd] = pd[i][hd];
        }
      }
    }
  }
}

// ---------------- Edge aggregation, H=2 (64 channels) ----------------
// Lane owns a channel PAIR (half2, 4B/lane); lanes 0-31 take edge i,
// 32-63 take edge i+1 -> 1 VMEM instr / 2 edges, pk_fma does 2 channels.
template<bool LN>
__global__ __launch_bounds__(256)
void gat_edge2(const float* __restrict__ h, const __half* __restrict__ hh,
               const float* __restrict__ sa, const float* __restrict__ da,
               const int* __restrict__ rowp, const int* __restrict__ col,
               const float* __restrict__ bias, const float* __restrict__ gamma,
               const float* __restrict__ beta, float* __restrict__ out, int N) {
  __shared__ __half2 wst[4][64][2];   // [wave][edge][head], each = (w,w)
  const int lane = (int)(threadIdx.x & 63);
  const int wib = (int)(threadIdx.x >> 6);
  int wv = (int)((blockIdx.x * blockDim.x + threadIdx.x) >> 6);
  const int n = __builtin_amdgcn_readfirstlane(wv);
  if (n >= N) return;
  const int c2 = lane & 31;        // channels 2*c2, 2*c2+1
  const int half = lane >> 5;      // which edge of the pair
  const int head = c2 >> 4;
  const int beg = __builtin_amdgcn_readfirstlane(rowp[n]);
  const int end = __builtin_amdgcn_readfirstlane(rowp[n + 1]);
  const float dv0 = da[n * 2];
  const float dv1 = da[n * 2 + 1];

  const __half2 z = __float2half2_rn(0.f);
  __half2 a0 = z, a1 = z, q0 = z, q1 = z;

  for (int b0 = beg; b0 < end; b0 += 64) {
    const int cnt = min(64, end - b0);
    if (lane < cnt) {
      const int s = col[b0 + lane];
      const float2 p = *(const float2*)(sa + (size_t)s * 2);
      wst[wib][lane][0] = __half2half2(__float2half(__expf(leaky(p.x + dv0))));
      wst[wib][lane][1] = __half2half2(__float2half(__expf(leaky(p.y + dv1))));
    }
    int i = 0;
    for (; i + 4 <= cnt; i += 4) {
      const int sA0 = col[b0 + i],     sA1 = col[b0 + i + 1];
      const int sB0 = col[b0 + i + 2], sB1 = col[b0 + i + 3];
      const int sA = half ? sA1 : sA0;
      const int sB = half ? sB1 : sB0;
      const __half2 wA = wst[wib][i + half][head];
      const __half2 wB = wst[wib][i + 2 + half][head];
      const __half2 hA = *(const __half2*)(hh + ((size_t)sA << 6) + 2 * c2);
      const __half2 hB = *(const __half2*)(hh + ((size_t)sB << 6) + 2 * c2);
      q0 = __hadd2(q0, wA);
      q1 = __hadd2(q1, wB);
      a0 = __hfma2(wA, hA, a0);
      a1 = __hfma2(wB, hB, a1);
    }
    if (i + 2 <= cnt) {
      const int s0 = col[b0 + i], s1 = col[b0 + i + 1];
      const int sA = half ? s1 : s0;
      const __half2 wA = wst[wib][i + half][head];
      const __half2 hA = *(const __half2*)(hh + ((size_t)sA << 6) + 2 * c2);
      q0 = __hadd2(q0, wA);
      a0 = __hfma2(wA, hA, a0);
      i += 2;
    }
    if (i < cnt) {   // single tail edge: half-0 lanes only
      const int s = col[b0 + i];
      const __half2 w = half ? z : wst[wib][i][head];
      const __half2 hv = *(const __half2*)(hh + ((size_t)s << 6) + 2 * c2);
      q0 = __hadd2(q0, w);
      a0 = __hfma2(w, hv, a0);
    }
  }

  float alo = __low2float(a0) + __low2float(a1);
  float ahi = __high2float(a0) + __high2float(a1);
  float qf  = __low2float(q0) + __low2float(q1);
  alo += __shfl_xor(alo, 32, 64);
  ahi += __shfl_xor(ahi, 32, 64);
  qf  += __shfl_xor(qf, 32, 64);

  const float inv = 1.f / fmaxf(qf, 1e-16f);
  const float2 hres = *(const float2*)(h + (size_t)n * 64 + 2 * c2);
  const float2 bi = *(const float2*)(bias + 2 * c2);
  float v0 = alo * inv + hres.x + bi.x;
  float v1 = ahi * inv + hres.y + bi.y;
  if constexpr (LN) {
    const float mu = wave_reduce_add64(v0 + v1) * (1.f / 128.f);
    const float d0 = v0 - mu, d1 = v1 - mu;
    const float var = wave_reduce_add64(d0 * d0 + d1 * d1) * (1.f / 128.f);
    const float rs = rsqrtf(var + 1e-5f);
    const float2 g = *(const float2*)(gamma + 2 * c2);
    const float2 be = *(const float2*)(beta + 2 * c2);
    v0 = fmaxf(d0 * rs * g.x + be.x, 0.f);
    v1 = fmaxf(d1 * rs * g.y + be.y, 0.f);
  }
  if (half == 0) {
    float2 o; o.x = v0; o.y = v1;
    *(float2*)(out + (size_t)n * 64 + 2 * c2) = o;
  }
}

// ---------------- Edge aggregation, H=1 (32 channels): 4 edges/step ----------------
__global__ __launch_bounds__(256)
void gat_edge1(const float* __restrict__ h, const __half* __restrict__ hh,
               const float* __restrict__ sa, const float* __restrict__ da,
               const int* __restrict__ rowp, const int* __restrict__ col,
               const float* __restrict__ bias, float* __restrict__ out, int N) {
  __shared__ __half2 wst[4][64];
  const int lane = (int)(threadIdx.x & 63);
  const int wib = (int)(threadIdx.x >> 6);
  int wv = (int)((blockIdx.x * blockDim.x + threadIdx.x) >> 6);
  const int n = __builtin_amdgcn_readfirstlane(wv);
  if (n >= N) return;
  const int c2 = lane & 15;        // channels 2*c2, 2*c2+1
  const int quarter = lane >> 4;   // which of 4 edges
  const int beg = __builtin_amdgcn_readfirstlane(rowp[n]);
  const int end = __builtin_amdgcn_readfirstlane(rowp[n + 1]);
  const float dv = da[n];

  const __half2 z = __float2half2_rn(0.f);
  __half2 a0 = z, a1 = z, q0 = z, q1 = z;

  for (int b0 = beg; b0 < end; b0 += 64) {
    const int cnt = min(64, end - b0);
    if (lane < cnt) {
      const int s = col[b0 + lane];
      wst[wib][lane] = __half2half2(__float2half(__expf(leaky(sa[s] + dv))));
    }
    int i = 0;
    for (; i + 8 <= cnt; i += 8) {
      const int sA = col[b0 + i + quarter];
      const int sB = col[b0 + i + 4 + quarter];
      const __half2 wA = wst[wib][i + quarter];
      const __half2 wB = wst[wib][i + 4 + quarter];
      const __half2 hA = *(const __half2*)(hh + ((size_t)sA << 5) + 2 * c2);
      const __half2 hB = *(const __half2*)(hh + ((size_t)sB << 5) + 2 * c2);
      q0 = __hadd2(q0, wA);
      q1 = __hadd2(q1, wB);
      a0 = __hfma2(wA, hA, a0);
      a1 = __hfma2(wB, hB, a1);
    }
    if (i + 4 <= cnt) {
      const int sA = col[b0 + i + quarter];
      const __half2 wA = wst[wib][i + quarter];
      const __half2 hA = *(const __half2*)(hh + ((size_t)sA << 5) + 2 * c2);
      q0 = __hadd2(q0, wA);
      a0 = __hfma2(wA, hA, a0);
      i += 4;
    }
    for (; i < cnt; ++i) {  // tails: quarter-0 lanes carry the weight
      const int s = col[b0 + i];
      const __half2 w = quarter ? z : wst[wib][i];
      const __half2 hv = *(const __half2*)(hh + ((size_t)s << 5) + 2 * c2);
      q0 = __hadd2(q0, w);
      a0 = __hfma2(w, hv, a0);
    }
  }

  float alo = __low2float(a0) + __low2float(a1);
  float ahi = __high2float(a0) + __high2float(a1);
  float qf  = __low2float(q0) + __low2float(q1);
  #pragma unroll
  for (int m = 16; m < 64; m <<= 1) {
    alo += __shfl_xor(alo, m, 64);
    ahi += __shfl_xor(ahi, m, 64);
    qf  += __shfl_xor(qf, m, 64);
  }

  if (quarter == 0) {
    const float inv = 1.f / fmaxf(qf, 1e-16f);
    const float2 hres = *(const float2*)(h + (size_t)n * 32 + 2 * c2);
    const float2 bi = *(const float2*)(bias + 2 * c2);
    float2 o;
    o.x = alo * inv + hres.x + bi.x;
    o.y = ahi * inv + hres.y + bi.y;
    *(float2*)(out + (size_t)n * 32 + 2 * c2) = o;
  }
}

// ---------------- CSR build: LDS-staged radix partition ----------------
__global__ __launch_bounds__(256)
void k_hist_chunk(const int* __restrict__ dst, int* __restrict__ bcnt, int E, int NB) {
  __shared__ int lh[NBMAX];
  const int t = (int)threadIdx.x;
  const int c0 = (int)blockIdx.x * CHUNK;
  const int cnt = min(CHUNK, E - c0);
  for (int b = t; b < NB; b += 256) lh[b] = 0;
  __syncthreads();
  for (int i = t; i < cnt; i += 256)
    atomicAdd(&lh[dst[c0 + i] >> BSH], 1);
  __syncthreads();
  for (int b = t; b < NB; b += 256)
    if (lh[b]) atomicAdd(&bcnt[b], lh[b]);
}

__global__ void k_bscan(const int* __restrict__ bcnt, int nb,
                        int* __restrict__ bstart, int* __restrict__ bcur,
                        int* __restrict__ rowp_last, int E) {
  __shared__ int sm[256];
  const int t = (int)threadIdx.x;
  int v[4];
  #pragma unroll
  for (int j = 0; j < 4; ++j) { int i = t * 4 + j; v[j] = (i < nb) ? bcnt[i] : 0; }
  const int tot = v[0] + v[1] + v[2] + v[3];
  sm[t] = tot; __syncthreads();
  #pragma unroll
  for (int off = 1; off < 256; off <<= 1) {
    int xv = (t >= off) ? sm[t - off] : 0;
    __syncthreads();
    sm[t] += xv;
    __syncthreads();
  }
  int excl = sm[t] - tot;
  #pragma unroll
  for (int j = 0; j < 4; ++j) {
    int i = t * 4 + j;
    if (i < nb) { bstart[i] = excl; bcur[i] = excl; excl += v[j]; }
  }
  if (t == 0) { bstart[nb] = E; *rowp_last = E; }
}

__global__ __launch_bounds__(256)
void k_part(const int* __restrict__ src, const int* __restrict__ dst,
            int* __restrict__ bcur, int* __restrict__ pairs, int E, int NB) {
  __shared__ int lh[NBMAX];
  __shared__ int lofs[NBMAX];
  __shared__ int gofs[NBMAX];
  __shared__ int stg[CHUNK];
  __shared__ short stgb[CHUNK];
  __shared__ int bsum[256];
  const int t = (int)threadIdx.x;
  const int c0 = (int)blockIdx.x * CHUNK;
  const int cnt = min(CHUNK, E - c0);

  for (int b = t; b < NB; b += 256) lh[b] = 0;
  __syncthreads();
  for (int i = t; i < cnt; i += 256)
    atomicAdd(&lh[dst[c0 + i] >> BSH], 1);
  __syncthreads();

  int v[4]; int run = 0;
  #pragma unroll
  for (int j = 0; j < 4; ++j) {
    const int b = t * 4 + j;
    v[j] = (b < NB) ? lh[b] : 0;
    run += v[j];
  }
  bsum[t] = run;
  __syncthreads();
  #pragma unroll
  for (int off = 1; off < 256; off <<= 1) {
    int xv = (t >= off) ? bsum[t - off] : 0;
    __syncthreads();
    bsum[t] += xv;
    __syncthreads();
  }
  int base = bsum[t] - run;
  #pragma unroll
  for (int j = 0; j < 4; ++j) {
    const int b = t * 4 + j;
    if (b < NB) lofs[b] = base;
    base += v[j];
  }
  __syncthreads();

  for (int b = t; b < NB; b += 256) {
    const int c = lh[b];
    gofs[b] = c ? atomicAdd(&bcur[b], c) : 0;
    lh[b] = lofs[b];
  }
  __syncthreads();

  for (int i = t; i < cnt; i += 256) {
    const int d = dst[c0 + i];
    const int b = d >> BSH;
    const int p = atomicAdd(&lh[b], 1);
    stg[p] = (src[c0 + i] << BSH) | (d & (BN - 1));
    stgb[p] = (short)b;
  }
  __syncthreads();

  for (int i = t; i < cnt; i += 256) {
    const int b = (int)stgb[i];
    pairs[gofs[b] + (i - lofs[b])] = stg[i];
  }
}

__global__ __launch_bounds__(256)
void k_bucket_csr(const int* __restrict__ pairs, const int* __restrict__ bstart,
                  int* __restrict__ rowp, int* __restrict__ col, int N) {
  __shared__ int ldeg[BN];
  __shared__ int lofs[BN];
  const int b = (int)blockIdx.x;
  const int t = (int)threadIdx.x;
  const int base = b << BSH;
  const int nn = min(BN, N - base);
  const int s0 = bstart[b];
  const int s1 = bstart[b + 1];

  if (t < BN) ldeg[t] = 0;
  __syncthreads();
  for (int i = s0 + t; i < s1; i += 256)
    atomicAdd(&ldeg[pairs[i] & (BN - 1)], 1);
  __syncthreads();
  if (t < BN) lofs[t] = ldeg[t];
  __syncthreads();
  #pragma unroll
  for (int off = 1; off < BN; off <<= 1) {
    int v = (t < BN && t >= off) ? lofs[t - off] : 0;
    __syncthreads();
    if (t < BN) lofs[t] += v;
    __syncthreads();
  }
  if (t < BN) {
    const int ofs = s0 + lofs[t] - ldeg[t];
    if (t < nn) rowp[base + t] = ofs;
    ldeg[t] = ofs;
  }
  __syncthreads();
  for (int i = s0 + t; i < s1; i += 256) {
    const int pr = pairs[i];
    const int p = atomicAdd(&ldeg[pr & (BN - 1)], 1);
    col[p] = pr >> BSH;
  }
}

extern "C" void kernel_launch(void* const* d_in, const int* in_sizes, int n_in,
                              void* d_out, int out_size, void* d_ws, size_t ws_size,
                              hipStream_t stream) {
  const float* x   = (const float*)d_in[0];
  const int* esrc  = (const int*)d_in[1];
  const int* edst  = (const int*)d_in[2];
  const float* W1  = (const float*)d_in[3];
  const float* as1 = (const float*)d_in[4];
  const float* ad1 = (const float*)d_in[5];
  const float* b1  = (const float*)d_in[6];
  const float* W2  = (const float*)d_in[7];
  const float* as2 = (const float*)d_in[8];
  const float* ad2 = (const float*)d_in[9];
  const float* b2  = (const float*)d_in[10];
  const float* W3  = (const float*)d_in[11];
  const float* as3 = (const float*)d_in[12];
  const float* ad3 = (const float*)d_in[13];
  const float* b3  = (const float*)d_in[14];
  const float* g1  = (const float*)d_in[15];
  const float* be1 = (const float*)d_in[16];
  const float* g2  = (const float*)d_in[17];
  const float* be2 = (const float*)d_in[18];

  const int N = in_sizes[0] / 128;
  const int E = in_sizes[1];
  const int NB = (N + BN - 1) / BN;

  char* ws = (char*)d_ws;
  size_t off = 0;
  auto alloc = [&](size_t bytes) -> void* {
    void* p = ws + off;
    off = (off + bytes + 255) & ~(size_t)255;
    return p;
  };
  float* hbuf  = (float*)alloc((size_t)N * 64 * 4);
  float* lnbuf = (float*)alloc((size_t)N * 64 * 4);
  __half* hh   = (__half*)alloc((size_t)N * 64 * 2);
  float* sab   = (float*)alloc((size_t)N * 2 * 4);
  float* dab   = (float*)alloc((size_t)N * 2 * 4);
  int* rowp    = (int*)alloc((size_t)(N + 1) * 4);
  int* colb    = (int*)alloc((size_t)E * 4);
  int* bcnt    = (int*)alloc((size_t)NB * 4);
  int* bstart  = (int*)alloc((size_t)(NB + 1) * 4);
  int* bcur    = (int*)alloc((size_t)NB * 4);
  // pairs buffer: reuse d_out (N*32 floats = 12.8MB >= E*4 = 6.4MB);
  // lifetime ends before the final layer writes d_out.
  int* pairs = (E <= out_size) ? (int*)d_out : (int*)alloc((size_t)E * 4);
  (void)ws_size; (void)n_in;

  // ---- CSR build (contention-free radix partition) ----
  hipMemsetAsync(bcnt, 0, (size_t)NB * 4, stream);
  const int NW = (E + CHUNK - 1) / CHUNK;
  k_hist_chunk<<<NW, 256, 0, stream>>>(edst, bcnt, E, NB);
  k_bscan<<<1, 256, 0, stream>>>(bcnt, NB, bstart, bcur, rowp + N, E);
  k_part<<<NW, 256, 0, stream>>>(esrc, edst, bcur, pairs, E, NB);
  k_bucket_csr<<<NB, 256, 0, stream>>>(pairs, bstart, rowp, colb, N);

  const int gG12 = (N + 63) / 64;
  const int gG3  = (N + 127) / 128;
  const int gEdge = (N + 3) / 4;   // one wave per node

  // ---- Layer 1: 128 -> (2x32) + LN + ReLU ----
  gat_gemm2<128, 64, 2><<<gG12, 256, 0, stream>>>(x, W1, as1, ad1, hbuf, hh, sab, dab, N);
  gat_edge2<true><<<gEdge, 256, 0, stream>>>(hbuf, hh, sab, dab, rowp, colb, b1, g1, be1, lnbuf, N);

  // ---- Layer 2: 64 -> (2x32) + LN + ReLU ----
  gat_gemm2<64, 64, 2><<<gG12, 256, 0, stream>>>(lnbuf, W2, as2, ad2, hbuf, hh, sab, dab, N);
  gat_edge2<true><<<gEdge, 256, 0, stream>>>(hbuf, hh, sab, dab, rowp, colb, b2, g2, be2, lnbuf, N);

  // ---- Layer 3: 64 -> (1x32), no LN ----
  gat_gemm2<64, 32, 1><<<gG3, 256, 0, stream>>>(lnbuf, W3, as3, ad3, hbuf, hh, sab, dab, N);
  gat_edge1<<<gEdge, 256, 0, stream>>>(hbuf, hh, sab, dab, rowp, colb, b3, (float*)d_out, N);
}

// Round 8
// 279.942 us; speedup vs baseline: 1.2005x; 1.2005x over previous
//
#include <hip/hip_runtime.h>
#include <hip/hip_fp16.h>

#define LEAKY 0.2f
#define BSH 7
#define BN 128      // nodes per bucket = 1<<BSH
#define CHUNK 8192  // edges per partition workgroup
#define NBMAX 1024  // max buckets supported by LDS arrays

__device__ __forceinline__ float leaky(float l) {
  return l >= 0.f ? l : LEAKY * l;
}

// sum across a 32-lane half-wave (xor masks < 32 never cross the half boundary)
__device__ __forceinline__ float half_reduce_add32(float v) {
  #pragma unroll
  for (int m = 1; m < 32; m <<= 1) v += __shfl_xor(v, m, 64);
  return v;
}

__device__ __forceinline__ __half2 splat_sel(int wbits, int hi) {
  __half2 wp = *(__half2*)&wbits;
  return __half2half2(hi ? __high2half(wp) : __low2half(wp));
}

// ---------------- Tiled GEMM + fused attention dots (+ fp16 mirror of h) ----------------
template<int K, int CO, int H>
__global__ __launch_bounds__(256)
void gat_gemm2(const float* __restrict__ x, const float* __restrict__ W,
               const float* __restrict__ atts, const float* __restrict__ attd,
               float* __restrict__ h, __half* __restrict__ hh,
               float* __restrict__ sa, float* __restrict__ da, int N) {
  constexpr int CG = CO / 4;
  constexpr int BM = (256 / CG) * 4;
  constexpr int BK = 64;
  constexpr int NK = K / BK;
  constexpr int C = CO / H;

  __shared__ float xs[BM][BK + 4];
  __shared__ float ws[CO][K + 4];

  const int t = (int)threadIdx.x;
  const int cg = t % CG;
  const int ng = t / CG;
  const int n0 = (int)blockIdx.x * BM;

  constexpr int WF4 = CO * K / 4;
  for (int f = t; f < WF4; f += 256) {
    const int r = f / (K / 4), c4 = f % (K / 4);
    *(float4*)&ws[r][c4 * 4] = *(const float4*)(W + (size_t)r * K + c4 * 4);
  }

  float acc[4][4] = {};

  for (int kb = 0; kb < NK; ++kb) {
    __syncthreads();
    constexpr int XF4 = BM * BK / 4;
    for (int f = t; f < XF4; f += 256) {
      const int r = f / (BK / 4), c4 = f % (BK / 4);
      int row = n0 + r; row = row < N ? row : N - 1;
      *(float4*)&xs[r][c4 * 4] = *(const float4*)(x + (size_t)row * K + kb * BK + c4 * 4);
    }
    __syncthreads();
    #pragma unroll
    for (int k = 0; k < BK; k += 4) {
      float4 xa[4], wb[4];
      #pragma unroll
      for (int i = 0; i < 4; ++i) xa[i] = *(const float4*)&xs[ng * 4 + i][k];
      #pragma unroll
      for (int j = 0; j < 4; ++j) wb[j] = *(const float4*)&ws[cg + CG * j][kb * BK + k];
      #pragma unroll
      for (int i = 0; i < 4; ++i) {
        #pragma unroll
        for (int j = 0; j < 4; ++j) {
          acc[i][j] = fmaf(xa[i].x, wb[j].x, acc[i][j]);
          acc[i][j] = fmaf(xa[i].y, wb[j].y, acc[i][j]);
          acc[i][j] = fmaf(xa[i].z, wb[j].z, acc[i][j]);
          acc[i][j] = fmaf(xa[i].w, wb[j].w, acc[i][j]);
        }
      }
    }
  }

  float as_[4], ad_[4];
  #pragma unroll
  for (int j = 0; j < 4; ++j) {
    as_[j] = atts[cg + CG * j];
    ad_[j] = attd[cg + CG * j];
  }
  float ps[4][H] = {}, pd[4][H] = {};
  #pragma unroll
  for (int i = 0; i < 4; ++i) {
    #pragma unroll
    for (int j = 0; j < 4; ++j) {
      const int hd = (CG * j) / C;
      ps[i][hd] = fmaf(acc[i][j], as_[j], ps[i][hd]);
      pd[i][hd] = fmaf(acc[i][j], ad_[j], pd[i][hd]);
    }
  }
  #pragma unroll
  for (int m = 1; m < CG; m <<= 1) {
    #pragma unroll
    for (int i = 0; i < 4; ++i) {
      #pragma unroll
      for (int hd = 0; hd < H; ++hd) {
        ps[i][hd] += __shfl_xor(ps[i][hd], m, 64);
        pd[i][hd] += __shfl_xor(pd[i][hd], m, 64);
      }
    }
  }

  #pragma unroll
  for (int i = 0; i < 4; ++i) {
    const int n = n0 + ng * 4 + i;
    if (n < N) {
      #pragma unroll
      for (int j = 0; j < 4; ++j) {
        h[(size_t)n * CO + cg + CG * j] = acc[i][j];
        hh[(size_t)n * CO + cg + CG * j] = __float2half(acc[i][j]);
      }
      if (cg == 0) {
        #pragma unroll
        for (int hd = 0; hd < H; ++hd) {
          sa[n * H + hd] = ps[i][hd];
          da[n * H + hd] = pd[i][hd];
        }
      }
    }
  }
}

// ---------------- Edge aggregation, H=2 (64 ch): 2 nodes per wave ----------------
// Each half-wave owns one node; lane = channel pair (half2). Every lane walks
// ALL edges of its node -> no cross-lane merge. w-phase packs (src, w0w1)
// into LDS; inner loop = ds_read_b64 + 128B gather + pk_fma. LN over 32 lanes.
template<bool LN>
__global__ __launch_bounds__(256)
void gat_edge2(const float* __restrict__ h, const __half* __restrict__ hh,
               const float* __restrict__ sa, const float* __restrict__ da,
               const int* __restrict__ rowp, const int* __restrict__ col,
               const float* __restrict__ bias, const float* __restrict__ gamma,
               const float* __restrict__ beta, float* __restrict__ out, int N) {
  __shared__ int2 wst[4][2][32];
  const int t = (int)threadIdx.x;
  const int lane = t & 63;
  const int wib = t >> 6;
  const int half = lane >> 5;
  const int l = lane & 31;          // channel-pair index (channels 2l, 2l+1)
  const int head = l >> 4;
  const int wgl = (int)((blockIdx.x * blockDim.x + t) >> 6);
  const int n = wgl * 2 + half;
  const bool valid = (n < N);
  const int nc = valid ? n : N - 1;
  const int beg = rowp[nc];
  const int end = rowp[nc + 1];
  const float2 dvv = *(const float2*)(da + (size_t)nc * 2);
  const __half2* __restrict__ hhp = (const __half2*)hh;

  const __half2 z = __float2half2_rn(0.f);
  __half2 a0 = z, a1 = z, a2 = z, a3 = z, q0 = z, q1 = z;

  for (int b0 = beg; b0 < end; b0 += 32) {
    const int cnt = min(32, end - b0);
    if (l < cnt) {
      const int s = col[b0 + l];
      const float2 p = *(const float2*)(sa + (size_t)s * 2);
      const __half2 wp = __halves2half2(__float2half(__expf(leaky(p.x + dvv.x))),
                                        __float2half(__expf(leaky(p.y + dvv.y))));
      int2 ent; ent.x = s; ent.y = *(const int*)&wp;
      wst[wib][half][l] = ent;
    }
    int i = 0;
    for (; i + 4 <= cnt; i += 4) {
      const int2 e0 = wst[wib][half][i];
      const int2 e1 = wst[wib][half][i + 1];
      const int2 e2 = wst[wib][half][i + 2];
      const int2 e3 = wst[wib][half][i + 3];
      const __half2 w0 = splat_sel(e0.y, head);
      const __half2 w1 = splat_sel(e1.y, head);
      const __half2 w2 = splat_sel(e2.y, head);
      const __half2 w3 = splat_sel(e3.y, head);
      const __half2 h0 = hhp[((size_t)e0.x << 5) + l];
      const __half2 h1 = hhp[((size_t)e1.x << 5) + l];
      const __half2 h2 = hhp[((size_t)e2.x << 5) + l];
      const __half2 h3 = hhp[((size_t)e3.x << 5) + l];
      q0 = __hadd2(q0, __hadd2(w0, w1));
      q1 = __hadd2(q1, __hadd2(w2, w3));
      a0 = __hfma2(w0, h0, a0);
      a1 = __hfma2(w1, h1, a1);
      a2 = __hfma2(w2, h2, a2);
      a3 = __hfma2(w3, h3, a3);
    }
    for (; i < cnt; ++i) {
      const int2 e = wst[wib][half][i];
      const __half2 w = splat_sel(e.y, head);
      const __half2 hv = hhp[((size_t)e.x << 5) + l];
      q0 = __hadd2(q0, w);
      a0 = __hfma2(w, hv, a0);
    }
  }

  const float alo = (__low2float(a0) + __low2float(a1)) + (__low2float(a2) + __low2float(a3));
  const float ahi = (__high2float(a0) + __high2float(a1)) + (__high2float(a2) + __high2float(a3));
  const float qf = __low2float(q0) + __low2float(q1);   // identical in all lanes of the half

  const float inv = 1.f / fmaxf(qf, 1e-16f);
  const float2 hres = *(const float2*)(h + (size_t)nc * 64 + 2 * l);
  const float2 bi = *(const float2*)(bias + 2 * l);
  float v0 = alo * inv + hres.x + bi.x;
  float v1 = ahi * inv + hres.y + bi.y;
  if constexpr (LN) {
    const float mu = half_reduce_add32(v0 + v1) * (1.f / 64.f);
    const float d0 = v0 - mu, d1 = v1 - mu;
    const float var = half_reduce_add32(d0 * d0 + d1 * d1) * (1.f / 64.f);
    const float rs = rsqrtf(var + 1e-5f);
    const float2 g = *(const float2*)(gamma + 2 * l);
    const float2 be = *(const float2*)(beta + 2 * l);
    v0 = fmaxf(d0 * rs * g.x + be.x, 0.f);
    v1 = fmaxf(d1 * rs * g.y + be.y, 0.f);
  }
  if (valid) {
    float2 o; o.x = v0; o.y = v1;
    *(float2*)(out + (size_t)n * 64 + 2 * l) = o;
  }
}

// ---------------- Edge aggregation, H=1 (32 ch): 4 nodes per wave ----------------
__global__ __launch_bounds__(256)
void gat_edge1(const float* __restrict__ h, const __half* __restrict__ hh,
               const float* __restrict__ sa, const float* __restrict__ da,
               const int* __restrict__ rowp, const int* __restrict__ col,
               const float* __restrict__ bias, float* __restrict__ out, int N) {
  __shared__ int2 wst[4][4][16];
  const int t = (int)threadIdx.x;
  const int lane = t & 63;
  const int wib = t >> 6;
  const int quarter = lane >> 4;
  const int l = lane & 15;          // channel-pair index (channels 2l, 2l+1)
  const int wgl = (int)((blockIdx.x * blockDim.x + t) >> 6);
  const int n = wgl * 4 + quarter;
  const bool valid = (n < N);
  const int nc = valid ? n : N - 1;
  const int beg = rowp[nc];
  const int end = rowp[nc + 1];
  const float dv = da[nc];
  const __half2* __restrict__ hhp = (const __half2*)hh;

  const __half2 z = __float2half2_rn(0.f);
  __half2 a0 = z, a1 = z, a2 = z, a3 = z, q0 = z, q1 = z;

  for (int b0 = beg; b0 < end; b0 += 16) {
    const int cnt = min(16, end - b0);
    if (l < cnt) {
      const int s = col[b0 + l];
      const __half2 wsp = __half2half2(__float2half(__expf(leaky(sa[s] + dv))));
      int2 ent; ent.x = s; ent.y = *(const int*)&wsp;
      wst[wib][quarter][l] = ent;
    }
    int i = 0;
    for (; i + 4 <= cnt; i += 4) {
      const int2 e0 = wst[wib][quarter][i];
      const int2 e1 = wst[wib][quarter][i + 1];
      const int2 e2 = wst[wib][quarter][i + 2];
      const int2 e3 = wst[wib][quarter][i + 3];
      const __half2 w0 = *(const __half2*)&e0.y;
      const __half2 w1 = *(const __half2*)&e1.y;
      const __half2 w2 = *(const __half2*)&e2.y;
      const __half2 w3 = *(const __half2*)&e3.y;
      const __half2 h0 = hhp[((size_t)e0.x << 4) + l];
      const __half2 h1 = hhp[((size_t)e1.x << 4) + l];
      const __half2 h2 = hhp[((size_t)e2.x << 4) + l];
      const __half2 h3 = hhp[((size_t)e3.x << 4) + l];
      q0 = __hadd2(q0, __hadd2(w0, w1));
      q1 = __hadd2(q1, __hadd2(w2, w3));
      a0 = __hfma2(w0, h0, a0);
      a1 = __hfma2(w1, h1, a1);
      a2 = __hfma2(w2, h2, a2);
      a3 = __hfma2(w3, h3, a3);
    }
    for (; i < cnt; ++i) {
      const int2 e = wst[wib][quarter][i];
      const __half2 w = *(const __half2*)&e.y;
      const __half2 hv = hhp[((size_t)e.x << 4) + l];
      q0 = __hadd2(q0, w);
      a0 = __hfma2(w, hv, a0);
    }
  }

  const float alo = (__low2float(a0) + __low2float(a1)) + (__low2float(a2) + __low2float(a3));
  const float ahi = (__high2float(a0) + __high2float(a1)) + (__high2float(a2) + __high2float(a3));
  const float qf = __low2float(q0) + __low2float(q1);

  if (valid) {
    const float inv = 1.f / fmaxf(qf, 1e-16f);
    const float2 hres = *(const float2*)(h + (size_t)n * 32 + 2 * l);
    const float2 bi = *(const float2*)(bias + 2 * l);
    float2 o;
    o.x = alo * inv + hres.x + bi.x;
    o.y = ahi * inv + hres.y + bi.y;
    *(float2*)(out + (size_t)n * 32 + 2 * l) = o;
  }
}

// ---------------- CSR build: LDS-staged radix partition ----------------
__global__ __launch_bounds__(256)
void k_hist_chunk(const int* __restrict__ dst, int* __restrict__ bcnt, int E, int NB) {
  __shared__ int lh[NBMAX];
  const int t = (int)threadIdx.x;
  const int c0 = (int)blockIdx.x * CHUNK;
  const int cnt = min(CHUNK, E - c0);
  for (int b = t; b < NB; b += 256) lh[b] = 0;
  __syncthreads();
  for (int i = t; i < cnt; i += 256)
    atomicAdd(&lh[dst[c0 + i] >> BSH], 1);
  __syncthreads();
  for (int b = t; b < NB; b += 256)
    if (lh[b]) atomicAdd(&bcnt[b], lh[b]);
}

__global__ void k_bscan(const int* __restrict__ bcnt, int nb,
                        int* __restrict__ bstart, int* __restrict__ bcur,
                        int* __restrict__ rowp_last, int E) {
  __shared__ int sm[256];
  const int t = (int)threadIdx.x;
  int v[4];
  #pragma unroll
  for (int j = 0; j < 4; ++j) { int i = t * 4 + j; v[j] = (i < nb) ? bcnt[i] : 0; }
  const int tot = v[0] + v[1] + v[2] + v[3];
  sm[t] = tot; __syncthreads();
  #pragma unroll
  for (int off = 1; off < 256; off <<= 1) {
    int xv = (t >= off) ? sm[t - off] : 0;
    __syncthreads();
    sm[t] += xv;
    __syncthreads();
  }
  int excl = sm[t] - tot;
  #pragma unroll
  for (int j = 0; j < 4; ++j) {
    int i = t * 4 + j;
    if (i < nb) { bstart[i] = excl; bcur[i] = excl; excl += v[j]; }
  }
  if (t == 0) { bstart[nb] = E; *rowp_last = E; }
}

__global__ __launch_bounds__(256)
void k_part(const int* __restrict__ src, const int* __restrict__ dst,
            int* __restrict__ bcur, int* __restrict__ pairs, int E, int NB) {
  __shared__ int lh[NBMAX];
  __shared__ int lofs[NBMAX];
  __shared__ int gofs[NBMAX];
  __shared__ int stg[CHUNK];
  __shared__ short stgb[CHUNK];
  __shared__ int bsum[256];
  const int t = (int)threadIdx.x;
  const int c0 = (int)blockIdx.x * CHUNK;
  const int cnt = min(CHUNK, E - c0);

  for (int b = t; b < NB; b += 256) lh[b] = 0;
  __syncthreads();
  for (int i = t; i < cnt; i += 256)
    atomicAdd(&lh[dst[c0 + i] >> BSH], 1);
  __syncthreads();

  int v[4]; int run = 0;
  #pragma unroll
  for (int j = 0; j < 4; ++j) {
    const int b = t * 4 + j;
    v[j] = (b < NB) ? lh[b] : 0;
    run += v[j];
  }
  bsum[t] = run;
  __syncthreads();
  #pragma unroll
  for (int off = 1; off < 256; off <<= 1) {
    int xv = (t >= off) ? bsum[t - off] : 0;
    __syncthreads();
    bsum[t] += xv;
    __syncthreads();
  }
  int base = bsum[t] - run;
  #pragma unroll
  for (int j = 0; j < 4; ++j) {
    const int b = t * 4 + j;
    if (b < NB) lofs[b] = base;
    base += v[j];
  }
  __syncthreads();

  for (int b = t; b < NB; b += 256) {
    const int c = lh[b];
    gofs[b] = c ? atomicAdd(&bcur[b], c) : 0;
    lh[b] = lofs[b];
  }
  __syncthreads();

  for (int i = t; i < cnt; i += 256) {
    const int d = dst[c0 + i];
    const int b = d >> BSH;
    const int p = atomicAdd(&lh[b], 1);
    stg[p] = (src[c0 + i] << BSH) | (d & (BN - 1));
    stgb[p] = (short)b;
  }
  __syncthreads();

  for (int i = t; i < cnt; i += 256) {
    const int b = (int)stgb[i];
    pairs[gofs[b] + (i - lofs[b])] = stg[i];
  }
}

__global__ __launch_bounds__(256)
void k_bucket_csr(const int* __restrict__ pairs, const int* __restrict__ bstart,
                  int* __restrict__ rowp, int* __restrict__ col, int N) {
  __shared__ int ldeg[BN];
  __shared__ int lofs[BN];
  const int b = (int)blockIdx.x;
  const int t = (int)threadIdx.x;
  const int base = b << BSH;
  const int nn = min(BN, N - base);
  const int s0 = bstart[b];
  const int s1 = bstart[b + 1];

  if (t < BN) ldeg[t] = 0;
  __syncthreads();
  for (int i = s0 + t; i < s1; i += 256)
    atomicAdd(&ldeg[pairs[i] & (BN - 1)], 1);
  __syncthreads();
  if (t < BN) lofs[t] = ldeg[t];
  __syncthreads();
  #pragma unroll
  for (int off = 1; off < BN; off <<= 1) {
    int v = (t < BN && t >= off) ? lofs[t - off] : 0;
    __syncthreads();
    if (t < BN) lofs[t] += v;
    __syncthreads();
  }
  if (t < BN) {
    const int ofs = s0 + lofs[t] - ldeg[t];
    if (t < nn) rowp[base + t] = ofs;
    ldeg[t] = ofs;
  }
  __syncthreads();
  for (int i = s0 + t; i < s1; i += 256) {
    const int pr = pairs[i];
    const int p = atomicAdd(&ldeg[pr & (BN - 1)], 1);
    col[p] = pr >> BSH;
  }
}

extern "C" void kernel_launch(void* const* d_in, const int* in_sizes, int n_in,
                              void* d_out, int out_size, void* d_ws, size_t ws_size,
                              hipStream_t stream) {
  const float* x   = (const float*)d_in[0];
  const int* esrc  = (const int*)d_in[1];
  const int* edst  = (const int*)d_in[2];
  const float* W1  = (const float*)d_in[3];
  const float* as1 = (const float*)d_in[4];
  const float* ad1 = (const float*)d_in[5];
  const float* b1  = (const float*)d_in[6];
  const float* W2  = (const float*)d_in[7];
  const float* as2 = (const float*)d_in[8];
  const float* ad2 = (const float*)d_in[9];
  const float* b2  = (const float*)d_in[10];
  const float* W3  = (const float*)d_in[11];
  const float* as3 = (const float*)d_in[12];
  const float* ad3 = (const float*)d_in[13];
  const float* b3  = (const float*)d_in[14];
  const float* g1  = (const float*)d_in[15];
  const float* be1 = (const float*)d_in[16];
  const float* g2  = (const float*)d_in[17];
  const float* be2 = (const float*)d_in[18];

  const int N = in_sizes[0] / 128;
  const int E = in_sizes[1];
  const int NB = (N + BN - 1) / BN;

  char* ws = (char*)d_ws;
  size_t off = 0;
  auto alloc = [&](size_t bytes) -> void* {
    void* p = ws + off;
    off = (off + bytes + 255) & ~(size_t)255;
    return p;
  };
  float* hbuf  = (float*)alloc((size_t)N * 64 * 4);
  float* lnbuf = (float*)alloc((size_t)N * 64 * 4);
  __half* hh   = (__half*)alloc((size_t)N * 64 * 2);
  float* sab   = (float*)alloc((size_t)N * 2 * 4);
  float* dab   = (float*)alloc((size_t)N * 2 * 4);
  int* rowp    = (int*)alloc((size_t)(N + 1) * 4);
  int* colb    = (int*)alloc((size_t)E * 4);
  int* bcnt    = (int*)alloc((size_t)NB * 4);
  int* bstart  = (int*)alloc((size_t)(NB + 1) * 4);
  int* bcur    = (int*)alloc((size_t)NB * 4);
  // pairs buffer: reuse d_out (N*32 floats = 12.8MB >= E*4 = 6.4MB);
  // lifetime ends before the final layer writes d_out.
  int* pairs = (E <= out_size) ? (int*)d_out : (int*)alloc((size_t)E * 4);
  (void)ws_size; (void)n_in;

  // ---- CSR build (contention-free radix partition) ----
  hipMemsetAsync(bcnt, 0, (size_t)NB * 4, stream);
  const int NW = (E + CHUNK - 1) / CHUNK;
  k_hist_chunk<<<NW, 256, 0, stream>>>(edst, bcnt, E, NB);
  k_bscan<<<1, 256, 0, stream>>>(bcnt, NB, bstart, bcur, rowp + N, E);
  k_part<<<NW, 256, 0, stream>>>(esrc, edst, bcur, pairs, E, NB);
  k_bucket_csr<<<NB, 256, 0, stream>>>(pairs, bstart, rowp, colb, N);

  const int gG12 = (N + 63) / 64;
  const int gG3  = (N + 127) / 128;
  const int gE2 = (N + 7) / 8;     // 2 nodes/wave * 4 waves/block
  const int gE1 = (N + 15) / 16;   // 4 nodes/wave * 4 waves/block

  // ---- Layer 1: 128 -> (2x32) + LN + ReLU ----
  gat_gemm2<128, 64, 2><<<gG12, 256, 0, stream>>>(x, W1, as1, ad1, hbuf, hh, sab, dab, N);
  gat_edge2<true><<<gE2, 256, 0, stream>>>(hbuf, hh, sab, dab, rowp, colb, b1, g1, be1, lnbuf, N);

  // ---- Layer 2: 64 -> (2x32) + LN + ReLU ----
  gat_gemm2<64, 64, 2><<<gG12, 256, 0, stream>>>(lnbuf, W2, as2, ad2, hbuf, hh, sab, dab, N);
  gat_edge2<true><<<gE2, 256, 0, stream>>>(hbuf, hh, sab, dab, rowp, colb, b2, g2, be2, lnbuf, N);

  // ---- Layer 3: 64 -> (1x32), no LN ----
  gat_gemm2<64, 32, 1><<<gG3, 256, 0, stream>>>(lnbuf, W3, as3, ad3, hbuf, hh, sab, dab, N);
  gat_edge1<<<gE1, 256, 0, stream>>>(hbuf, hh, sab, dab, rowp, colb, b3, (float*)d_out, N);
}

// Round 9
// 246.168 us; speedup vs baseline: 1.3652x; 1.1372x over previous
//
#include <hip/hip_runtime.h>
#include <hip/hip_fp16.h>

#define LEAKY 0.2f
#define BSH 7
#define BN 128      // nodes per bucket = 1<<BSH
#define CHUNK 8192  // edges per partition workgroup
#define NBMAX 1024  // max buckets supported by LDS arrays

__device__ __forceinline__ float leaky(float l) {
  return l >= 0.f ? l : LEAKY * l;
}

__device__ __forceinline__ float half_reduce_add32(float v) {
  #pragma unroll
  for (int m = 1; m < 32; m <<= 1) v += __shfl_xor(v, m, 64);
  return v;
}

__device__ __forceinline__ __half2 splat_sel(int wbits, int hi) {
  __half2 wp = *(__half2*)&wbits;
  return __half2half2(hi ? __high2half(wp) : __low2half(wp));
}

typedef _Float16 f16x2 __attribute__((ext_vector_type(2)));

// fp32 += dot(2xfp16, 2xfp16) — v_dot2_f32_f16 (fp32 accumulate)
__device__ __forceinline__ float fdot2(unsigned a, unsigned b, float c) {
#if __has_builtin(__builtin_amdgcn_fdot2)
  return __builtin_amdgcn_fdot2(__builtin_bit_cast(f16x2, a),
                                __builtin_bit_cast(f16x2, b), c, false);
#else
  __half2 ha = *(__half2*)&a, hb = *(__half2*)&b;
  float2 fa = __half22float2(ha), fb = __half22float2(hb);
  return fmaf(fa.x, fb.x, fmaf(fa.y, fb.y, c));
#endif
}

// ---------------- Tiled GEMM (fp16 LDS operands, dot2 inner) ----------------
// LDS = 18.4-23 KB/block -> 6-8 blocks/CU. Thread tile 4 nodes x 4 channels.
template<int K, int CO, int H, bool IN_F32>
__global__ __launch_bounds__(256, 6)
void gat_gemm3(const void* __restrict__ xin, const float* __restrict__ W,
               const float* __restrict__ atts, const float* __restrict__ attd,
               float* __restrict__ h, __half* __restrict__ hh,
               float* __restrict__ sa, float* __restrict__ da, int N) {
  constexpr int CG = CO / 4;          // 16 or 8
  constexpr int BM = (256 / CG) * 4;  // 64 or 128
  constexpr int BK = 64;
  constexpr int NK = K / BK;
  constexpr int C = CO / H;
  constexpr int LDW = BK / 2 + 4;     // 36 uints: 16B-aligned rows, benign banks

  __shared__ unsigned xs[BM][LDW];
  __shared__ unsigned ws[CO][LDW];

  const int t = (int)threadIdx.x;
  const int cg = t % CG;
  const int ng = t / CG;
  const int n0 = (int)blockIdx.x * BM;

  float acc[4][4] = {};

  for (int kb = 0; kb < NK; ++kb) {
    __syncthreads();
    // ---- stage x chunk (fp32->fp16 convert, or raw fp16 copy) ----
    if constexpr (IN_F32) {
      const float* x = (const float*)xin;
      constexpr int F4R = BK / 4;       // float4 per row
      constexpr int TOT = BM * F4R;
      for (int f = t; f < TOT; f += 256) {
        const int r = f / F4R, c = f % F4R;
        int row = n0 + r; row = row < N ? row : N - 1;
        const float4 v = *(const float4*)(x + (size_t)row * K + kb * BK + c * 4);
        const __half2 h0 = __floats2half2_rn(v.x, v.y);
        const __half2 h1 = __floats2half2_rn(v.z, v.w);
        xs[r][c * 2]     = *(const unsigned*)&h0;
        xs[r][c * 2 + 1] = *(const unsigned*)&h1;
      }
    } else {
      const __half* x = (const __half*)xin;
      constexpr int U4R = BK / 8;       // uint4 per row
      constexpr int TOT = BM * U4R;
      for (int f = t; f < TOT; f += 256) {
        const int r = f / U4R, c = f % U4R;
        int row = n0 + r; row = row < N ? row : N - 1;
        const uint4 v = *(const uint4*)(x + (size_t)row * K + kb * BK + c * 8);
        *(uint4*)&xs[r][c * 4] = v;
      }
    }
    // ---- stage W chunk (fp32->fp16) ----
    {
      constexpr int F4R = BK / 4;
      constexpr int TOT = CO * F4R;
      for (int f = t; f < TOT; f += 256) {
        const int r = f / F4R, c = f % F4R;
        const float4 v = *(const float4*)(W + (size_t)r * K + kb * BK + c * 4);
        const __half2 h0 = __floats2half2_rn(v.x, v.y);
        const __half2 h1 = __floats2half2_rn(v.z, v.w);
        ws[r][c * 2]     = *(const unsigned*)&h0;
        ws[r][c * 2 + 1] = *(const unsigned*)&h1;
      }
    }
    __syncthreads();
    #pragma unroll
    for (int k = 0; k < BK; k += 8) {
      uint4 xa[4], wb[4];
      #pragma unroll
      for (int i = 0; i < 4; ++i) xa[i] = *(const uint4*)&xs[ng * 4 + i][k / 2];
      #pragma unroll
      for (int j = 0; j < 4; ++j) wb[j] = *(const uint4*)&ws[cg + CG * j][k / 2];
      #pragma unroll
      for (int i = 0; i < 4; ++i) {
        #pragma unroll
        for (int j = 0; j < 4; ++j) {
          acc[i][j] = fdot2(xa[i].x, wb[j].x, acc[i][j]);
          acc[i][j] = fdot2(xa[i].y, wb[j].y, acc[i][j]);
          acc[i][j] = fdot2(xa[i].z, wb[j].z, acc[i][j]);
          acc[i][j] = fdot2(xa[i].w, wb[j].w, acc[i][j]);
        }
      }
    }
  }

  // ---- fused sa/da + stores ----
  float as_[4], ad_[4];
  #pragma unroll
  for (int j = 0; j < 4; ++j) {
    as_[j] = atts[cg + CG * j];
    ad_[j] = attd[cg + CG * j];
  }
  float ps[4][H] = {}, pd[4][H] = {};
  #pragma unroll
  for (int i = 0; i < 4; ++i) {
    #pragma unroll
    for (int j = 0; j < 4; ++j) {
      const int hd = (CG * j) / C;
      ps[i][hd] = fmaf(acc[i][j], as_[j], ps[i][hd]);
      pd[i][hd] = fmaf(acc[i][j], ad_[j], pd[i][hd]);
    }
  }
  #pragma unroll
  for (int m = 1; m < CG; m <<= 1) {
    #pragma unroll
    for (int i = 0; i < 4; ++i) {
      #pragma unroll
      for (int hd = 0; hd < H; ++hd) {
        ps[i][hd] += __shfl_xor(ps[i][hd], m, 64);
        pd[i][hd] += __shfl_xor(pd[i][hd], m, 64);
      }
    }
  }

  #pragma unroll
  for (int i = 0; i < 4; ++i) {
    const int n = n0 + ng * 4 + i;
    if (n < N) {
      #pragma unroll
      for (int j = 0; j < 4; ++j) {
        h[(size_t)n * CO + cg + CG * j] = acc[i][j];
        hh[(size_t)n * CO + cg + CG * j] = __float2half(acc[i][j]);
      }
      if (cg == 0) {
        #pragma unroll
        for (int hd = 0; hd < H; ++hd) {
          sa[n * H + hd] = ps[i][hd];
          da[n * H + hd] = pd[i][hd];
        }
      }
    }
  }
}

// ---------------- Edge aggregation, H=2 (64 ch): 2 nodes per wave ----------------
// out is fp16 (lnbuf) — it is only consumed as the next GEMM's input.
__global__ __launch_bounds__(256)
void gat_edge2(const float* __restrict__ h, const __half* __restrict__ hh,
               const float* __restrict__ sa, const float* __restrict__ da,
               const int* __restrict__ rowp, const int* __restrict__ col,
               const float* __restrict__ bias, const float* __restrict__ gamma,
               const float* __restrict__ beta, __half* __restrict__ out, int N) {
  __shared__ int2 wst[4][2][32];
  const int t = (int)threadIdx.x;
  const int lane = t & 63;
  const int wib = t >> 6;
  const int half = lane >> 5;
  const int l = lane & 31;          // channel-pair index (channels 2l, 2l+1)
  const int head = l >> 4;
  const int wgl = (int)((blockIdx.x * blockDim.x + t) >> 6);
  const int n = wgl * 2 + half;
  const bool valid = (n < N);
  const int nc = valid ? n : N - 1;
  const int beg = rowp[nc];
  const int end = rowp[nc + 1];
  const float2 dvv = *(const float2*)(da + (size_t)nc * 2);
  const __half2* __restrict__ hhp = (const __half2*)hh;

  const __half2 z = __float2half2_rn(0.f);
  __half2 a0 = z, a1 = z, a2 = z, a3 = z, q0 = z, q1 = z;

  for (int b0 = beg; b0 < end; b0 += 32) {
    const int cnt = min(32, end - b0);
    if (l < cnt) {
      const int s = col[b0 + l];
      const float2 p = *(const float2*)(sa + (size_t)s * 2);
      const __half2 wp = __halves2half2(__float2half(__expf(leaky(p.x + dvv.x))),
                                        __float2half(__expf(leaky(p.y + dvv.y))));
      int2 ent; ent.x = s; ent.y = *(const int*)&wp;
      wst[wib][half][l] = ent;
    }
    int i = 0;
    for (; i + 4 <= cnt; i += 4) {
      const int2 e0 = wst[wib][half][i];
      const int2 e1 = wst[wib][half][i + 1];
      const int2 e2 = wst[wib][half][i + 2];
      const int2 e3 = wst[wib][half][i + 3];
      const __half2 w0 = splat_sel(e0.y, head);
      const __half2 w1 = splat_sel(e1.y, head);
      const __half2 w2 = splat_sel(e2.y, head);
      const __half2 w3 = splat_sel(e3.y, head);
      const __half2 h0 = hhp[((size_t)e0.x << 5) + l];
      const __half2 h1 = hhp[((size_t)e1.x << 5) + l];
      const __half2 h2 = hhp[((size_t)e2.x << 5) + l];
      const __half2 h3 = hhp[((size_t)e3.x << 5) + l];
      q0 = __hadd2(q0, __hadd2(w0, w1));
      q1 = __hadd2(q1, __hadd2(w2, w3));
      a0 = __hfma2(w0, h0, a0);
      a1 = __hfma2(w1, h1, a1);
      a2 = __hfma2(w2, h2, a2);
      a3 = __hfma2(w3, h3, a3);
    }
    for (; i < cnt; ++i) {
      const int2 e = wst[wib][half][i];
      const __half2 w = splat_sel(e.y, head);
      const __half2 hv = hhp[((size_t)e.x << 5) + l];
      q0 = __hadd2(q0, w);
      a0 = __hfma2(w, hv, a0);
    }
  }

  const float alo = (__low2float(a0) + __low2float(a1)) + (__low2float(a2) + __low2float(a3));
  const float ahi = (__high2float(a0) + __high2float(a1)) + (__high2float(a2) + __high2float(a3));
  const float qf = __low2float(q0) + __low2float(q1);

  const float inv = 1.f / fmaxf(qf, 1e-16f);
  const float2 hres = *(const float2*)(h + (size_t)nc * 64 + 2 * l);
  const float2 bi = *(const float2*)(bias + 2 * l);
  float v0 = alo * inv + hres.x + bi.x;
  float v1 = ahi * inv + hres.y + bi.y;
  {
    const float mu = half_reduce_add32(v0 + v1) * (1.f / 64.f);
    const float d0 = v0 - mu, d1 = v1 - mu;
    const float var = half_reduce_add32(d0 * d0 + d1 * d1) * (1.f / 64.f);
    const float rs = rsqrtf(var + 1e-5f);
    const float2 g = *(const float2*)(gamma + 2 * l);
    const float2 be = *(const float2*)(beta + 2 * l);
    v0 = fmaxf(d0 * rs * g.x + be.x, 0.f);
    v1 = fmaxf(d1 * rs * g.y + be.y, 0.f);
  }
  if (valid) {
    const __half2 o = __floats2half2_rn(v0, v1);
    *(__half2*)(out + (size_t)n * 64 + 2 * l) = o;
  }
}

// ---------------- Edge aggregation, H=1 (32 ch): 4 nodes per wave ----------------
__global__ __launch_bounds__(256)
void gat_edge1(const float* __restrict__ h, const __half* __restrict__ hh,
               const float* __restrict__ sa, const float* __restrict__ da,
               const int* __restrict__ rowp, const int* __restrict__ col,
               const float* __restrict__ bias, float* __restrict__ out, int N) {
  __shared__ int2 wst[4][4][16];
  const int t = (int)threadIdx.x;
  const int lane = t & 63;
  const int wib = t >> 6;
  const int quarter = lane >> 4;
  const int l = lane & 15;
  const int wgl = (int)((blockIdx.x * blockDim.x + t) >> 6);
  const int n = wgl * 4 + quarter;
  const bool valid = (n < N);
  const int nc = valid ? n : N - 1;
  const int beg = rowp[nc];
  const int end = rowp[nc + 1];
  const float dv = da[nc];
  const __half2* __restrict__ hhp = (const __half2*)hh;

  const __half2 z = __float2half2_rn(0.f);
  __half2 a0 = z, a1 = z, a2 = z, a3 = z, q0 = z, q1 = z;

  for (int b0 = beg; b0 < end; b0 += 16) {
    const int cnt = min(16, end - b0);
    if (l < cnt) {
      const int s = col[b0 + l];
      const __half2 wsp = __half2half2(__float2half(__expf(leaky(sa[s] + dv))));
      int2 ent; ent.x = s; ent.y = *(const int*)&wsp;
      wst[wib][quarter][l] = ent;
    }
    int i = 0;
    for (; i + 4 <= cnt; i += 4) {
      const int2 e0 = wst[wib][quarter][i];
      const int2 e1 = wst[wib][quarter][i + 1];
      const int2 e2 = wst[wib][quarter][i + 2];
      const int2 e3 = wst[wib][quarter][i + 3];
      const __half2 w0 = *(const __half2*)&e0.y;
      const __half2 w1 = *(const __half2*)&e1.y;
      const __half2 w2 = *(const __half2*)&e2.y;
      const __half2 w3 = *(const __half2*)&e3.y;
      const __half2 h0 = hhp[((size_t)e0.x << 4) + l];
      const __half2 h1 = hhp[((size_t)e1.x << 4) + l];
      const __half2 h2 = hhp[((size_t)e2.x << 4) + l];
      const __half2 h3 = hhp[((size_t)e3.x << 4) + l];
      q0 = __hadd2(q0, __hadd2(w0, w1));
      q1 = __hadd2(q1, __hadd2(w2, w3));
      a0 = __hfma2(w0, h0, a0);
      a1 = __hfma2(w1, h1, a1);
      a2 = __hfma2(w2, h2, a2);
      a3 = __hfma2(w3, h3, a3);
    }
    for (; i < cnt; ++i) {
      const int2 e = wst[wib][quarter][i];
      const __half2 w = *(const __half2*)&e.y;
      const __half2 hv = hhp[((size_t)e.x << 4) + l];
      q0 = __hadd2(q0, w);
      a0 = __hfma2(w, hv, a0);
    }
  }

  const float alo = (__low2float(a0) + __low2float(a1)) + (__low2float(a2) + __low2float(a3));
  const float ahi = (__high2float(a0) + __high2float(a1)) + (__high2float(a2) + __high2float(a3));
  const float qf = __low2float(q0) + __low2float(q1);

  if (valid) {
    const float inv = 1.f / fmaxf(qf, 1e-16f);
    const float2 hres = *(const float2*)(h + (size_t)n * 32 + 2 * l);
    const float2 bi = *(const float2*)(bias + 2 * l);
    float2 o;
    o.x = alo * inv + hres.x + bi.x;
    o.y = ahi * inv + hres.y + bi.y;
    *(float2*)(out + (size_t)n * 32 + 2 * l) = o;
  }
}

// ---------------- CSR build: LDS-staged radix partition ----------------
__global__ __launch_bounds__(256)
void k_hist_chunk(const int* __restrict__ dst, int* __restrict__ bcnt, int E, int NB) {
  __shared__ int lh[NBMAX];
  const int t = (int)threadIdx.x;
  const int c0 = (int)blockIdx.x * CHUNK;
  const int cnt = min(CHUNK, E - c0);
  for (int b = t; b < NB; b += 256) lh[b] = 0;
  __syncthreads();
  for (int i = t; i < cnt; i += 256)
    atomicAdd(&lh[dst[c0 + i] >> BSH], 1);
  __syncthreads();
  for (int b = t; b < NB; b += 256)
    if (lh[b]) atomicAdd(&bcnt[b], lh[b]);
}

__global__ void k_bscan(const int* __restrict__ bcnt, int nb,
                        int* __restrict__ bstart, int* __restrict__ bcur,
                        int* __restrict__ rowp_last, int E) {
  __shared__ int sm[256];
  const int t = (int)threadIdx.x;
  int v[4];
  #pragma unroll
  for (int j = 0; j < 4; ++j) { int i = t * 4 + j; v[j] = (i < nb) ? bcnt[i] : 0; }
  const int tot = v[0] + v[1] + v[2] + v[3];
  sm[t] = tot; __syncthreads();
  #pragma unroll
  for (int off = 1; off < 256; off <<= 1) {
    int xv = (t >= off) ? sm[t - off] : 0;
    __syncthreads();
    sm[t] += xv;
    __syncthreads();
  }
  int excl = sm[t] - tot;
  #pragma unroll
  for (int j = 0; j < 4; ++j) {
    int i = t * 4 + j;
    if (i < nb) { bstart[i] = excl; bcur[i] = excl; excl += v[j]; }
  }
  if (t == 0) { bstart[nb] = E; *rowp_last = E; }
}

__global__ __launch_bounds__(256)
void k_part(const int* __restrict__ src, const int* __restrict__ dst,
            int* __restrict__ bcur, int* __restrict__ pairs, int E, int NB) {
  __shared__ int lh[NBMAX];
  __shared__ int lofs[NBMAX];
  __shared__ int gofs[NBMAX];
  __shared__ int stg[CHUNK];
  __shared__ short stgb[CHUNK];
  __shared__ int bsum[256];
  const int t = (int)threadIdx.x;
  const int c0 = (int)blockIdx.x * CHUNK;
  const int cnt = min(CHUNK, E - c0);

  for (int b = t; b < NB; b += 256) lh[b] = 0;
  __syncthreads();
  for (int i = t; i < cnt; i += 256)
    atomicAdd(&lh[dst[c0 + i] >> BSH], 1);
  __syncthreads();

  int v[4]; int run = 0;
  #pragma unroll
  for (int j = 0; j < 4; ++j) {
    const int b = t * 4 + j;
    v[j] = (b < NB) ? lh[b] : 0;
    run += v[j];
  }
  bsum[t] = run;
  __syncthreads();
  #pragma unroll
  for (int off = 1; off < 256; off <<= 1) {
    int xv = (t >= off) ? bsum[t - off] : 0;
    __syncthreads();
    bsum[t] += xv;
    __syncthreads();
  }
  int base = bsum[t] - run;
  #pragma unroll
  for (int j = 0; j < 4; ++j) {
    const int b = t * 4 + j;
    if (b < NB) lofs[b] = base;
    base += v[j];
  }
  __syncthreads();

  for (int b = t; b < NB; b += 256) {
    const int c = lh[b];
    gofs[b] = c ? atomicAdd(&bcur[b], c) : 0;
    lh[b] = lofs[b];
  }
  __syncthreads();

  for (int i = t; i < cnt; i += 256) {
    const int d = dst[c0 + i];
    const int b = d >> BSH;
    const int p = atomicAdd(&lh[b], 1);
    stg[p] = (src[c0 + i] << BSH) | (d & (BN - 1));
    stgb[p] = (short)b;
  }
  __syncthreads();

  for (int i = t; i < cnt; i += 256) {
    const int b = (int)stgb[i];
    pairs[gofs[b] + (i - lofs[b])] = stg[i];
  }
}

__global__ __launch_bounds__(256)
void k_bucket_csr(const int* __restrict__ pairs, const int* __restrict__ bstart,
                  int* __restrict__ rowp, int* __restrict__ col, int N) {
  __shared__ int ldeg[BN];
  __shared__ int lofs[BN];
  const int b = (int)blockIdx.x;
  const int t = (int)threadIdx.x;
  const int base = b << BSH;
  const int nn = min(BN, N - base);
  const int s0 = bstart[b];
  const int s1 = bstart[b + 1];

  if (t < BN) ldeg[t] = 0;
  __syncthreads();
  for (int i = s0 + t; i < s1; i += 256)
    atomicAdd(&ldeg[pairs[i] & (BN - 1)], 1);
  __syncthreads();
  if (t < BN) lofs[t] = ldeg[t];
  __syncthreads();
  #pragma unroll
  for (int off = 1; off < BN; off <<= 1) {
    int v = (t < BN && t >= off) ? lofs[t - off] : 0;
    __syncthreads();
    if (t < BN) lofs[t] += v;
    __syncthreads();
  }
  if (t < BN) {
    const int ofs = s0 + lofs[t] - ldeg[t];
    if (t < nn) rowp[base + t] = ofs;
    ldeg[t] = ofs;
  }
  __syncthreads();
  for (int i = s0 + t; i < s1; i += 256) {
    const int pr = pairs[i];
    const int p = atomicAdd(&ldeg[pr & (BN - 1)], 1);
    col[p] = pr >> BSH;
  }
}

extern "C" void kernel_launch(void* const* d_in, const int* in_sizes, int n_in,
                              void* d_out, int out_size, void* d_ws, size_t ws_size,
                              hipStream_t stream) {
  const float* x   = (const float*)d_in[0];
  const int* esrc  = (const int*)d_in[1];
  const int* edst  = (const int*)d_in[2];
  const float* W1  = (const float*)d_in[3];
  const float* as1 = (const float*)d_in[4];
  const float* ad1 = (const float*)d_in[5];
  const float* b1  = (const float*)d_in[6];
  const float* W2  = (const float*)d_in[7];
  const float* as2 = (const float*)d_in[8];
  const float* ad2 = (const float*)d_in[9];
  const float* b2  = (const float*)d_in[10];
  const float* W3  = (const float*)d_in[11];
  const float* as3 = (const float*)d_in[12];
  const float* ad3 = (const float*)d_in[13];
  const float* b3  = (const float*)d_in[14];
  const float* g1  = (const float*)d_in[15];
  const float* be1 = (const float*)d_in[16];
  const float* g2  = (const float*)d_in[17];
  const float* be2 = (const float*)d_in[18];

  const int N = in_sizes[0] / 128;
  const int E = in_sizes[1];
  const int NB = (N + BN - 1) / BN;

  char* ws = (char*)d_ws;
  size_t off = 0;
  auto alloc = [&](size_t bytes) -> void* {
    void* p = ws + off;
    off = (off + bytes + 255) & ~(size_t)255;
    return p;
  };
  float* hbuf  = (float*)alloc((size_t)N * 64 * 4);
  __half* lnbuf = (__half*)alloc((size_t)N * 64 * 2);
  __half* hh   = (__half*)alloc((size_t)N * 64 * 2);
  float* sab   = (float*)alloc((size_t)N * 2 * 4);
  float* dab   = (float*)alloc((size_t)N * 2 * 4);
  int* rowp    = (int*)alloc((size_t)(N + 1) * 4);
  int* colb    = (int*)alloc((size_t)E * 4);
  int* bcnt    = (int*)alloc((size_t)NB * 4);
  int* bstart  = (int*)alloc((size_t)(NB + 1) * 4);
  int* bcur    = (int*)alloc((size_t)NB * 4);
  // pairs buffer: reuse d_out (N*32 floats = 12.8MB >= E*4 = 6.4MB);
  // lifetime ends before the final layer writes d_out.
  int* pairs = (E <= out_size) ? (int*)d_out : (int*)alloc((size_t)E * 4);
  (void)ws_size; (void)n_in;

  // ---- CSR build (contention-free radix partition) ----
  hipMemsetAsync(bcnt, 0, (size_t)NB * 4, stream);
  const int NW = (E + CHUNK - 1) / CHUNK;
  k_hist_chunk<<<NW, 256, 0, stream>>>(edst, bcnt, E, NB);
  k_bscan<<<1, 256, 0, stream>>>(bcnt, NB, bstart, bcur, rowp + N, E);
  k_part<<<NW, 256, 0, stream>>>(esrc, edst, bcur, pairs, E, NB);
  k_bucket_csr<<<NB, 256, 0, stream>>>(pairs, bstart, rowp, colb, N);

  const int gG12 = (N + 63) / 64;    // BM=64
  const int gG3  = (N + 127) / 128;  // BM=128
  const int gE2 = (N + 7) / 8;       // 2 nodes/wave * 4 waves/block
  const int gE1 = (N + 15) / 16;     // 4 nodes/wave * 4 waves/block

  // ---- Layer 1: 128 -> (2x32) + LN + ReLU ----
  gat_gemm3<128, 64, 2, true><<<gG12, 256, 0, stream>>>(x, W1, as1, ad1, hbuf, hh, sab, dab, N);
  gat_edge2<<<gE2, 256, 0, stream>>>(hbuf, hh, sab, dab, rowp, colb, b1, g1, be1, lnbuf, N);

  // ---- Layer 2: 64 -> (2x32) + LN + ReLU ----
  gat_gemm3<64, 64, 2, false><<<gG12, 256, 0, stream>>>(lnbuf, W2, as2, ad2, hbuf, hh, sab, dab, N);
  gat_edge2<<<gE2, 256, 0, stream>>>(hbuf, hh, sab, dab, rowp, colb, b2, g2, be2, lnbuf, N);

  // ---- Layer 3: 64 -> (1x32), no LN ----
  gat_gemm3<64, 32, 1, false><<<gG3, 256, 0, stream>>>(lnbuf, W3, as3, ad3, hbuf, hh, sab, dab, N);
  gat_edge1<<<gE1, 256, 0, stream>>>(hbuf, hh, sab, dab, rowp, colb, b3, (float*)d_out, N);
}

// Round 10
// 235.130 us; speedup vs baseline: 1.4293x; 1.0469x over previous
//
#include <hip/hip_runtime.h>
#include <hip/hip_fp16.h>

#define LEAKY 0.2f
#define BSH 7
#define BN 128      // nodes per bucket = 1<<BSH
#define CHUNK 8192  // edges per partition workgroup
#define NBMAX 1024  // max buckets supported by LDS arrays

__device__ __forceinline__ float leaky(float l) {
  return l >= 0.f ? l : LEAKY * l;
}

typedef _Float16 f16x2 __attribute__((ext_vector_type(2)));

__device__ __forceinline__ float fdot2(unsigned a, unsigned b, float c) {
#if __has_builtin(__builtin_amdgcn_fdot2)
  return __builtin_amdgcn_fdot2(__builtin_bit_cast(f16x2, a),
                                __builtin_bit_cast(f16x2, b), c, false);
#else
  __half2 ha = *(__half2*)&a, hb = *(__half2*)&b;
  float2 fa = __half22float2(ha), fb = __half22float2(hb);
  return fmaf(fa.x, fb.x, fmaf(fa.y, fb.y, c));
#endif
}

__device__ __forceinline__ int packsplat(float w) {
  const __half2 s = __half2half2(__float2half(w));
  return *(const int*)&s;
}
__device__ __forceinline__ __half2 asH2(unsigned u) { return *(__half2*)&u; }

// ---------------- Tiled GEMM (fp16 LDS operands, dot2 inner, fp16-only output) ----------------
template<int K, int CO, int H, bool IN_F32>
__global__ __launch_bounds__(256, 6)
void gat_gemm3(const void* __restrict__ xin, const float* __restrict__ W,
               const float* __restrict__ atts, const float* __restrict__ attd,
               __half* __restrict__ hh, float* __restrict__ sa, float* __restrict__ da,
               int N) {
  constexpr int CG = CO / 4;          // 16 or 8
  constexpr int BM = (256 / CG) * 4;  // 64 or 128
  constexpr int BK = 64;
  constexpr int NK = K / BK;
  constexpr int C = CO / H;
  constexpr int LDW = BK / 2 + 4;

  __shared__ unsigned xs[BM][LDW];
  __shared__ unsigned ws[CO][LDW];

  const int t = (int)threadIdx.x;
  const int cg = t % CG;
  const int ng = t / CG;
  const int n0 = (int)blockIdx.x * BM;

  float acc[4][4] = {};

  for (int kb = 0; kb < NK; ++kb) {
    __syncthreads();
    if constexpr (IN_F32) {
      const float* x = (const float*)xin;
      constexpr int F4R = BK / 4;
      constexpr int TOT = BM * F4R;
      for (int f = t; f < TOT; f += 256) {
        const int r = f / F4R, c = f % F4R;
        int row = n0 + r; row = row < N ? row : N - 1;
        const float4 v = *(const float4*)(x + (size_t)row * K + kb * BK + c * 4);
        const __half2 h0 = __floats2half2_rn(v.x, v.y);
        const __half2 h1 = __floats2half2_rn(v.z, v.w);
        xs[r][c * 2]     = *(const unsigned*)&h0;
        xs[r][c * 2 + 1] = *(const unsigned*)&h1;
      }
    } else {
      const __half* x = (const __half*)xin;
      constexpr int U4R = BK / 8;
      constexpr int TOT = BM * U4R;
      for (int f = t; f < TOT; f += 256) {
        const int r = f / U4R, c = f % U4R;
        int row = n0 + r; row = row < N ? row : N - 1;
        const uint4 v = *(const uint4*)(x + (size_t)row * K + kb * BK + c * 8);
        *(uint4*)&xs[r][c * 4] = v;
      }
    }
    {
      constexpr int F4R = BK / 4;
      constexpr int TOT = CO * F4R;
      for (int f = t; f < TOT; f += 256) {
        const int r = f / F4R, c = f % F4R;
        const float4 v = *(const float4*)(W + (size_t)r * K + kb * BK + c * 4);
        const __half2 h0 = __floats2half2_rn(v.x, v.y);
        const __half2 h1 = __floats2half2_rn(v.z, v.w);
        ws[r][c * 2]     = *(const unsigned*)&h0;
        ws[r][c * 2 + 1] = *(const unsigned*)&h1;
      }
    }
    __syncthreads();
    #pragma unroll
    for (int k = 0; k < BK; k += 8) {
      uint4 xa[4], wb[4];
      #pragma unroll
      for (int i = 0; i < 4; ++i) xa[i] = *(const uint4*)&xs[ng * 4 + i][k / 2];
      #pragma unroll
      for (int j = 0; j < 4; ++j) wb[j] = *(const uint4*)&ws[cg + CG * j][k / 2];
      #pragma unroll
      for (int i = 0; i < 4; ++i) {
        #pragma unroll
        for (int j = 0; j < 4; ++j) {
          acc[i][j] = fdot2(xa[i].x, wb[j].x, acc[i][j]);
          acc[i][j] = fdot2(xa[i].y, wb[j].y, acc[i][j]);
          acc[i][j] = fdot2(xa[i].z, wb[j].z, acc[i][j]);
          acc[i][j] = fdot2(xa[i].w, wb[j].w, acc[i][j]);
        }
      }
    }
  }

  float as_[4], ad_[4];
  #pragma unroll
  for (int j = 0; j < 4; ++j) {
    as_[j] = atts[cg + CG * j];
    ad_[j] = attd[cg + CG * j];
  }
  float ps[4][H] = {}, pd[4][H] = {};
  #pragma unroll
  for (int i = 0; i < 4; ++i) {
    #pragma unroll
    for (int j = 0; j < 4; ++j) {
      const int hd = (CG * j) / C;
      ps[i][hd] = fmaf(acc[i][j], as_[j], ps[i][hd]);
      pd[i][hd] = fmaf(acc[i][j], ad_[j], pd[i][hd]);
    }
  }
  #pragma unroll
  for (int m = 1; m < CG; m <<= 1) {
    #pragma unroll
    for (int i = 0; i < 4; ++i) {
      #pragma unroll
      for (int hd = 0; hd < H; ++hd) {
        ps[i][hd] += __shfl_xor(ps[i][hd], m, 64);
        pd[i][hd] += __shfl_xor(pd[i][hd], m, 64);
      }
    }
  }

  #pragma unroll
  for (int i = 0; i < 4; ++i) {
    const int n = n0 + ng * 4 + i;
    if (n < N) {
      #pragma unroll
      for (int j = 0; j < 4; ++j)
        hh[(size_t)n * CO + cg + CG * j] = __float2half(acc[i][j]);
      if (cg == 0) {
        #pragma unroll
        for (int hd = 0; hd < H; ++hd) {
          sa[n * H + hd] = ps[i][hd];
          da[n * H + hd] = pd[i][hd];
        }
      }
    }
  }
}

// ---------------- Edge aggregation, H=2 (64 ch): 4 nodes/wave (16-lane quarters) ----------------
// Lane owns 4 channels (8 B). One wave-wide VMEM instr = 4 edge rows.
// w-phase pre-splats per-head weights into LDS: {src, (w,w)} per (edge, head).
__global__ __launch_bounds__(256)
void gat_edge2(const __half* __restrict__ hh,
               const float* __restrict__ sa, const float* __restrict__ da,
               const int* __restrict__ rowp, const int* __restrict__ col,
               const float* __restrict__ bias, const float* __restrict__ gamma,
               const float* __restrict__ beta, __half* __restrict__ out, int N) {
  __shared__ int2 wst[4][4][17][2];   // [wave][quarter][edge(16)+pad][head]
  const int t = (int)threadIdx.x;
  const int lane = t & 63;
  const int wib = t >> 6;
  const int quarter = lane >> 4;
  const int l = lane & 15;            // channels 4l .. 4l+3
  const int headq = l >> 3;
  const int wgl = (int)((blockIdx.x * blockDim.x + t) >> 6);
  const int n = wgl * 4 + quarter;
  const bool valid = (n < N);
  const int nc = valid ? n : N - 1;
  const int beg = rowp[nc];
  const int end = rowp[nc + 1];
  const float2 dvv = *(const float2*)(da + (size_t)nc * 2);
  const __half2* __restrict__ hhp = (const __half2*)hh;

  const __half2 z = __float2half2_rn(0.f);
  __half2 aL0 = z, aH0 = z, aL1 = z, aH1 = z, aL2 = z, aH2 = z, aL3 = z, aH3 = z;
  __half2 q0 = z, q1 = z, q2 = z, q3 = z;

  for (int b0 = beg; b0 < end; b0 += 16) {
    const int cnt = min(16, end - b0);
    if (l < cnt) {
      const int s = col[b0 + l];
      const float2 p = *(const float2*)(sa + (size_t)s * 2);
      int2 e0; e0.x = s; e0.y = packsplat(__expf(leaky(p.x + dvv.x)));
      int2 e1; e1.x = s; e1.y = packsplat(__expf(leaky(p.y + dvv.y)));
      wst[wib][quarter][l][0] = e0;
      wst[wib][quarter][l][1] = e1;
    }
    int i = 0;
    for (; i + 4 <= cnt; i += 4) {
      const int2 e0 = wst[wib][quarter][i][headq];
      const int2 e1 = wst[wib][quarter][i + 1][headq];
      const int2 e2 = wst[wib][quarter][i + 2][headq];
      const int2 e3 = wst[wib][quarter][i + 3][headq];
      const uint2 h0 = *(const uint2*)(hhp + ((size_t)e0.x << 5) + 2 * l);
      const uint2 h1 = *(const uint2*)(hhp + ((size_t)e1.x << 5) + 2 * l);
      const uint2 h2 = *(const uint2*)(hhp + ((size_t)e2.x << 5) + 2 * l);
      const uint2 h3 = *(const uint2*)(hhp + ((size_t)e3.x << 5) + 2 * l);
      const __half2 w0 = asH2(e0.y), w1 = asH2(e1.y), w2 = asH2(e2.y), w3 = asH2(e3.y);
      q0 = __hadd2(q0, w0); q1 = __hadd2(q1, w1);
      q2 = __hadd2(q2, w2); q3 = __hadd2(q3, w3);
      aL0 = __hfma2(w0, asH2(h0.x), aL0); aH0 = __hfma2(w0, asH2(h0.y), aH0);
      aL1 = __hfma2(w1, asH2(h1.x), aL1); aH1 = __hfma2(w1, asH2(h1.y), aH1);
      aL2 = __hfma2(w2, asH2(h2.x), aL2); aH2 = __hfma2(w2, asH2(h2.y), aH2);
      aL3 = __hfma2(w3, asH2(h3.x), aL3); aH3 = __hfma2(w3, asH2(h3.y), aH3);
    }
    for (; i < cnt; ++i) {
      const int2 e = wst[wib][quarter][i][headq];
      const uint2 hv = *(const uint2*)(hhp + ((size_t)e.x << 5) + 2 * l);
      const __half2 w = asH2(e.y);
      q0 = __hadd2(q0, w);
      aL0 = __hfma2(w, asH2(hv.x), aL0);
      aH0 = __hfma2(w, asH2(hv.y), aH0);
    }
  }

  const float c0 = (__low2float(aL0) + __low2float(aL1)) + (__low2float(aL2) + __low2float(aL3));
  const float c1 = (__high2float(aL0) + __high2float(aL1)) + (__high2float(aL2) + __high2float(aL3));
  const float c2 = (__low2float(aH0) + __low2float(aH1)) + (__low2float(aH2) + __low2float(aH3));
  const float c3 = (__high2float(aH0) + __high2float(aH1)) + (__high2float(aH2) + __high2float(aH3));
  const float qf = (__low2float(q0) + __low2float(q1)) + (__low2float(q2) + __low2float(q3));

  const float inv = 1.f / fmaxf(qf, 1e-16f);
  const uint2 hr = *(const uint2*)(hhp + ((size_t)nc << 5) + 2 * l);
  const float2 r01 = __half22float2(asH2(hr.x));
  const float2 r23 = __half22float2(asH2(hr.y));
  const float4 bi = *(const float4*)(bias + 4 * l);
  float v0 = c0 * inv + r01.x + bi.x;
  float v1 = c1 * inv + r01.y + bi.y;
  float v2 = c2 * inv + r23.x + bi.z;
  float v3 = c3 * inv + r23.y + bi.w;
  {
    float s = (v0 + v1) + (v2 + v3);
    #pragma unroll
    for (int m = 1; m < 16; m <<= 1) s += __shfl_xor(s, m, 64);
    const float mu = s * (1.f / 64.f);
    const float d0 = v0 - mu, d1 = v1 - mu, d2 = v2 - mu, d3 = v3 - mu;
    float vs = (d0 * d0 + d1 * d1) + (d2 * d2 + d3 * d3);
    #pragma unroll
    for (int m = 1; m < 16; m <<= 1) vs += __shfl_xor(vs, m, 64);
    const float rs = rsqrtf(vs * (1.f / 64.f) + 1e-5f);
    const float4 g = *(const float4*)(gamma + 4 * l);
    const float4 be = *(const float4*)(beta + 4 * l);
    v0 = fmaxf(d0 * rs * g.x + be.x, 0.f);
    v1 = fmaxf(d1 * rs * g.y + be.y, 0.f);
    v2 = fmaxf(d2 * rs * g.z + be.z, 0.f);
    v3 = fmaxf(d3 * rs * g.w + be.w, 0.f);
  }
  if (valid) {
    const __half2 o01 = __floats2half2_rn(v0, v1);
    const __half2 o23 = __floats2half2_rn(v2, v3);
    uint2 o; o.x = *(const unsigned*)&o01; o.y = *(const unsigned*)&o23;
    *(uint2*)(out + (size_t)n * 64 + 4 * l) = o;
  }
}

// ---------------- Edge aggregation, H=1 (32 ch): 8 nodes/wave (8-lane octets) ----------------
__global__ __launch_bounds__(256)
void gat_edge1(const __half* __restrict__ hh,
               const float* __restrict__ sa, const float* __restrict__ da,
               const int* __restrict__ rowp, const int* __restrict__ col,
               const float* __restrict__ bias, float* __restrict__ out, int N) {
  __shared__ int2 wst[4][8][17];      // [wave][octet][edge(16)+pad]
  const int t = (int)threadIdx.x;
  const int lane = t & 63;
  const int wib = t >> 6;
  const int oct = lane >> 3;
  const int l = lane & 7;             // channels 4l .. 4l+3
  const int wgl = (int)((blockIdx.x * blockDim.x + t) >> 6);
  const int n = wgl * 8 + oct;
  const bool valid = (n < N);
  const int nc = valid ? n : N - 1;
  const int beg = rowp[nc];
  const int end = rowp[nc + 1];
  const float dv = da[nc];
  const __half2* __restrict__ hhp = (const __half2*)hh;

  const __half2 z = __float2half2_rn(0.f);
  __half2 aL0 = z, aH0 = z, aL1 = z, aH1 = z, aL2 = z, aH2 = z, aL3 = z, aH3 = z;
  __half2 q0 = z, q1 = z, q2 = z, q3 = z;

  for (int b0 = beg; b0 < end; b0 += 16) {
    const int cnt = min(16, end - b0);
    if (l < 8) {  // all octet lanes participate; 2 rounds of 8 edges
      if (l < cnt) {
        const int s = col[b0 + l];
        int2 e; e.x = s; e.y = packsplat(__expf(leaky(sa[s] + dv)));
        wst[wib][oct][l] = e;
      }
      const int l8 = l + 8;
      if (l8 < cnt) {
        const int s = col[b0 + l8];
        int2 e; e.x = s; e.y = packsplat(__expf(leaky(sa[s] + dv)));
        wst[wib][oct][l8] = e;
      }
    }
    int i = 0;
    for (; i + 4 <= cnt; i += 4) {
      const int2 e0 = wst[wib][oct][i];
      const int2 e1 = wst[wib][oct][i + 1];
      const int2 e2 = wst[wib][oct][i + 2];
      const int2 e3 = wst[wib][oct][i + 3];
      const uint2 h0 = *(const uint2*)(hhp + ((size_t)e0.x << 4) + 2 * l);
      const uint2 h1 = *(const uint2*)(hhp + ((size_t)e1.x << 4) + 2 * l);
      const uint2 h2 = *(const uint2*)(hhp + ((size_t)e2.x << 4) + 2 * l);
      const uint2 h3 = *(const uint2*)(hhp + ((size_t)e3.x << 4) + 2 * l);
      const __half2 w0 = asH2(e0.y), w1 = asH2(e1.y), w2 = asH2(e2.y), w3 = asH2(e3.y);
      q0 = __hadd2(q0, w0); q1 = __hadd2(q1, w1);
      q2 = __hadd2(q2, w2); q3 = __hadd2(q3, w3);
      aL0 = __hfma2(w0, asH2(h0.x), aL0); aH0 = __hfma2(w0, asH2(h0.y), aH0);
      aL1 = __hfma2(w1, asH2(h1.x), aL1); aH1 = __hfma2(w1, asH2(h1.y), aH1);
      aL2 = __hfma2(w2, asH2(h2.x), aL2); aH2 = __hfma2(w2, asH2(h2.y), aH2);
      aL3 = __hfma2(w3, asH2(h3.x), aL3); aH3 = __hfma2(w3, asH2(h3.y), aH3);
    }
    for (; i < cnt; ++i) {
      const int2 e = wst[wib][oct][i];
      const uint2 hv = *(const uint2*)(hhp + ((size_t)e.x << 4) + 2 * l);
      const __half2 w = asH2(e.y);
      q0 = __hadd2(q0, w);
      aL0 = __hfma2(w, asH2(hv.x), aL0);
      aH0 = __hfma2(w, asH2(hv.y), aH0);
    }
  }

  const float c0 = (__low2float(aL0) + __low2float(aL1)) + (__low2float(aL2) + __low2float(aL3));
  const float c1 = (__high2float(aL0) + __high2float(aL1)) + (__high2float(aL2) + __high2float(aL3));
  const float c2 = (__low2float(aH0) + __low2float(aH1)) + (__low2float(aH2) + __low2float(aH3));
  const float c3 = (__high2float(aH0) + __high2float(aH1)) + (__high2float(aH2) + __high2float(aH3));
  const float qf = (__low2float(q0) + __low2float(q1)) + (__low2float(q2) + __low2float(q3));

  if (valid) {
    const float inv = 1.f / fmaxf(qf, 1e-16f);
    const uint2 hr = *(const uint2*)(hhp + ((size_t)nc << 4) + 2 * l);
    const float2 r01 = __half22float2(asH2(hr.x));
    const float2 r23 = __half22float2(asH2(hr.y));
    const float4 bi = *(const float4*)(bias + 4 * l);
    float4 o;
    o.x = c0 * inv + r01.x + bi.x;
    o.y = c1 * inv + r01.y + bi.y;
    o.z = c2 * inv + r23.x + bi.z;
    o.w = c3 * inv + r23.y + bi.w;
    *(float4*)(out + (size_t)n * 32 + 4 * l) = o;
  }
}

// ---------------- CSR build: LDS-staged radix partition ----------------
__global__ __launch_bounds__(256)
void k_hist_chunk(const int* __restrict__ dst, int* __restrict__ bcnt, int E, int NB) {
  __shared__ int lh[NBMAX];
  const int t = (int)threadIdx.x;
  const int c0 = (int)blockIdx.x * CHUNK;
  const int cnt = min(CHUNK, E - c0);
  for (int b = t; b < NB; b += 256) lh[b] = 0;
  __syncthreads();
  for (int i = t; i < cnt; i += 256)
    atomicAdd(&lh[dst[c0 + i] >> BSH], 1);
  __syncthreads();
  for (int b = t; b < NB; b += 256)
    if (lh[b]) atomicAdd(&bcnt[b], lh[b]);
}

__global__ void k_bscan(const int* __restrict__ bcnt, int nb,
                        int* __restrict__ bstart, int* __restrict__ bcur,
                        int* __restrict__ rowp_last, int E) {
  __shared__ int sm[256];
  const int t = (int)threadIdx.x;
  int v[4];
  #pragma unroll
  for (int j = 0; j < 4; ++j) { int i = t * 4 + j; v[j] = (i < nb) ? bcnt[i] : 0; }
  const int tot = v[0] + v[1] + v[2] + v[3];
  sm[t] = tot; __syncthreads();
  #pragma unroll
  for (int off = 1; off < 256; off <<= 1) {
    int xv = (t >= off) ? sm[t - off] : 0;
    __syncthreads();
    sm[t] += xv;
    __syncthreads();
  }
  int excl = sm[t] - tot;
  #pragma unroll
  for (int j = 0; j < 4; ++j) {
    int i = t * 4 + j;
    if (i < nb) { bstart[i] = excl; bcur[i] = excl; excl += v[j]; }
  }
  if (t == 0) { bstart[nb] = E; *rowp_last = E; }
}

__global__ __launch_bounds__(256)
void k_part(const int* __restrict__ src, const int* __restrict__ dst,
            int* __restrict__ bcur, int* __restrict__ pairs, int E, int NB) {
  __shared__ int lh[NBMAX];
  __shared__ int lofs[NBMAX];
  __shared__ int gofs[NBMAX];
  __shared__ int stg[CHUNK];
  __shared__ short stgb[CHUNK];
  __shared__ int bsum[256];
  const int t = (int)threadIdx.x;
  const int c0 = (int)blockIdx.x * CHUNK;
  const int cnt = min(CHUNK, E - c0);

  for (int b = t; b < NB; b += 256) lh[b] = 0;
  __syncthreads();
  for (int i = t; i < cnt; i += 256)
    atomicAdd(&lh[dst[c0 + i] >> BSH], 1);
  __syncthreads();

  int v[4]; int run = 0;
  #pragma unroll
  for (int j = 0; j < 4; ++j) {
    const int b = t * 4 + j;
    v[j] = (b < NB) ? lh[b] : 0;
    run += v[j];
  }
  bsum[t] = run;
  __syncthreads();
  #pragma unroll
  for (int off = 1; off < 256; off <<= 1) {
    int xv = (t >= off) ? bsum[t - off] : 0;
    __syncthreads();
    bsum[t] += xv;
    __syncthreads();
  }
  int base = bsum[t] - run;
  #pragma unroll
  for (int j = 0; j < 4; ++j) {
    const int b = t * 4 + j;
    if (b < NB) lofs[b] = base;
    base += v[j];
  }
  __syncthreads();

  for (int b = t; b < NB; b += 256) {
    const int c = lh[b];
    gofs[b] = c ? atomicAdd(&bcur[b], c) : 0;
    lh[b] = lofs[b];
  }
  __syncthreads();

  for (int i = t; i < cnt; i += 256) {
    const int d = dst[c0 + i];
    const int b = d >> BSH;
    const int p = atomicAdd(&lh[b], 1);
    stg[p] = (src[c0 + i] << BSH) | (d & (BN - 1));
    stgb[p] = (short)b;
  }
  __syncthreads();

  for (int i = t; i < cnt; i += 256) {
    const int b = (int)stgb[i];
    pairs[gofs[b] + (i - lofs[b])] = stg[i];
  }
}

__global__ __launch_bounds__(256)
void k_bucket_csr(const int* __restrict__ pairs, const int* __restrict__ bstart,
                  int* __restrict__ rowp, int* __restrict__ col, int N) {
  __shared__ int ldeg[BN];
  __shared__ int lofs[BN];
  const int b = (int)blockIdx.x;
  const int t = (int)threadIdx.x;
  const int base = b << BSH;
  const int nn = min(BN, N - base);
  const int s0 = bstart[b];
  const int s1 = bstart[b + 1];

  if (t < BN) ldeg[t] = 0;
  __syncthreads();
  for (int i = s0 + t; i < s1; i += 256)
    atomicAdd(&ldeg[pairs[i] & (BN - 1)], 1);
  __syncthreads();
  if (t < BN) lofs[t] = ldeg[t];
  __syncthreads();
  #pragma unroll
  for (int off = 1; off < BN; off <<= 1) {
    int v = (t < BN && t >= off) ? lofs[t - off] : 0;
    __syncthreads();
    if (t < BN) lofs[t] += v;
    __syncthreads();
  }
  if (t < BN) {
    const int ofs = s0 + lofs[t] - ldeg[t];
    if (t < nn) rowp[base + t] = ofs;
    ldeg[t] = ofs;
  }
  __syncthreads();
  for (int i = s0 + t; i < s1; i += 256) {
    const int pr = pairs[i];
    const int p = atomicAdd(&ldeg[pr & (BN - 1)], 1);
    col[p] = pr >> BSH;
  }
}

extern "C" void kernel_launch(void* const* d_in, const int* in_sizes, int n_in,
                              void* d_out, int out_size, void* d_ws, size_t ws_size,
                              hipStream_t stream) {
  const float* x   = (const float*)d_in[0];
  const int* esrc  = (const int*)d_in[1];
  const int* edst  = (const int*)d_in[2];
  const float* W1  = (const float*)d_in[3];
  const float* as1 = (const float*)d_in[4];
  const float* ad1 = (const float*)d_in[5];
  const float* b1  = (const float*)d_in[6];
  const float* W2  = (const float*)d_in[7];
  const float* as2 = (const float*)d_in[8];
  const float* ad2 = (const float*)d_in[9];
  const float* b2  = (const float*)d_in[10];
  const float* W3  = (const float*)d_in[11];
  const float* as3 = (const float*)d_in[12];
  const float* ad3 = (const float*)d_in[13];
  const float* b3  = (const float*)d_in[14];
  const float* g1  = (const float*)d_in[15];
  const float* be1 = (const float*)d_in[16];
  const float* g2  = (const float*)d_in[17];
  const float* be2 = (const float*)d_in[18];

  const int N = in_sizes[0] / 128;
  const int E = in_sizes[1];
  const int NB = (N + BN - 1) / BN;

  char* ws = (char*)d_ws;
  size_t off = 0;
  auto alloc = [&](size_t bytes) -> void* {
    void* p = ws + off;
    off = (off + bytes + 255) & ~(size_t)255;
    return p;
  };
  __half* lnbuf = (__half*)alloc((size_t)N * 64 * 2);
  __half* hh   = (__half*)alloc((size_t)N * 64 * 2);
  float* sab   = (float*)alloc((size_t)N * 2 * 4);
  float* dab   = (float*)alloc((size_t)N * 2 * 4);
  int* rowp    = (int*)alloc((size_t)(N + 1) * 4);
  int* colb    = (int*)alloc((size_t)E * 4);
  int* bcnt    = (int*)alloc((size_t)NB * 4);
  int* bstart  = (int*)alloc((size_t)(NB + 1) * 4);
  int* bcur    = (int*)alloc((size_t)NB * 4);
  // pairs buffer: reuse d_out (N*32 floats = 12.8MB >= E*4 = 6.4MB);
  // lifetime ends before the final layer writes d_out.
  int* pairs = (E <= out_size) ? (int*)d_out : (int*)alloc((size_t)E * 4);
  (void)ws_size; (void)n_in;

  // ---- CSR build (contention-free radix partition) ----
  hipMemsetAsync(bcnt, 0, (size_t)NB * 4, stream);
  const int NW = (E + CHUNK - 1) / CHUNK;
  k_hist_chunk<<<NW, 256, 0, stream>>>(edst, bcnt, E, NB);
  k_bscan<<<1, 256, 0, stream>>>(bcnt, NB, bstart, bcur, rowp + N, E);
  k_part<<<NW, 256, 0, stream>>>(esrc, edst, bcur, pairs, E, NB);
  k_bucket_csr<<<NB, 256, 0, stream>>>(pairs, bstart, rowp, colb, N);

  const int gG12 = (N + 63) / 64;    // BM=64
  const int gG3  = (N + 127) / 128;  // BM=128
  const int gE2 = (N + 15) / 16;     // 4 nodes/wave * 4 waves/block
  const int gE1 = (N + 31) / 32;     // 8 nodes/wave * 4 waves/block

  // ---- Layer 1: 128 -> (2x32) + LN + ReLU ----
  gat_gemm3<128, 64, 2, true><<<gG12, 256, 0, stream>>>(x, W1, as1, ad1, hh, sab, dab, N);
  gat_edge2<<<gE2, 256, 0, stream>>>(hh, sab, dab, rowp, colb, b1, g1, be1, lnbuf, N);

  // ---- Layer 2: 64 -> (2x32) + LN + ReLU ----
  gat_gemm3<64, 64, 2, false><<<gG12, 256, 0, stream>>>(lnbuf, W2, as2, ad2, hh, sab, dab, N);
  gat_edge2<<<gE2, 256, 0, stream>>>(hh, sab, dab, rowp, colb, b2, g2, be2, lnbuf, N);

  // ---- Layer 3: 64 -> (1x32), no LN ----
  gat_gemm3<64, 32, 1, false><<<gG3, 256, 0, stream>>>(lnbuf, W3, as3, ad3, hh, sab, dab, N);
  gat_edge1<<<gE1, 256, 0, stream>>>(hh, sab, dab, rowp, colb, b3, (float*)d_out, N);
}